// Round 5
// baseline (857.348 us; speedup 1.0000x reference)
//
#include <hip/hip_runtime.h>
#include <hip/hip_bf16.h>
#include <math.h>

// ---------------------------------------------------------------------------
// Shapes (fixed by the problem)
// ---------------------------------------------------------------------------
#define B_    4
#define S_    512
#define D_    1024
#define T_    2048          // B*S tokens
#define H_    16
#define HD_   64
#define E_    8
#define HID_  1792
#define D3_   3072
#define GU_   (2 * HID_)    // 3584 interleaved gate/up columns

typedef unsigned short ushort_t;
typedef __bf16 bf16x8 __attribute__((ext_vector_type(8)));
typedef float  floatx4 __attribute__((ext_vector_type(4)));

__device__ inline float bf2f(ushort_t u) {
    return __uint_as_float(((unsigned)u) << 16);
}
__device__ inline ushort_t f2bf(float f) {
    __hip_bfloat16 h = __float2bfloat16(f);
    return __builtin_bit_cast(ushort_t, h);
}

// async 16B/lane global->LDS; lds dest wave-uniform base (+lane*16 by HW)
__device__ __forceinline__ void gl2lds16(const ushort_t* g, ushort_t* l) {
    __builtin_amdgcn_global_load_lds(
        (const __attribute__((address_space(1))) void*)g,
        (__attribute__((address_space(3))) void*)l, 16, 0, 0);
}

// ---------------------------------------------------------------------------
// Transpose + fp32->bf16: in (z,R,C) f32 -> out[z*outEstride + (c*mul+add)*R + r]
// ---------------------------------------------------------------------------
__global__ __launch_bounds__(256) void transpose_bf16_kernel(
    const float* __restrict__ in, ushort_t* __restrict__ out,
    int R, int C, int mul, int add, long outEstride)
{
    __shared__ float tile[32][33];
    const int bx = blockIdx.x * 32;           // c
    const int by = blockIdx.y * 32;           // r
    const size_t iofs = (size_t)blockIdx.z * R * C;
    const size_t oofs = (size_t)blockIdx.z * outEstride;
    const int tx = threadIdx.x & 31;
    const int ty = threadIdx.x >> 5;          // 0..7
#pragma unroll
    for (int i = 0; i < 4; i++) {
        int r = by + ty + i * 8;
        tile[ty + i * 8][tx] = in[iofs + (size_t)r * C + bx + tx];
    }
    __syncthreads();
#pragma unroll
    for (int i = 0; i < 4; i++) {
        int c = bx + ty + i * 8;
        out[oofs + (size_t)(c * mul + add) * R + by + tx] = f2bf(tile[tx][ty + i * 8]);
    }
}

// ---------------------------------------------------------------------------
// LayerNorm: x (rows x 1024) f32 -> f32 out and/or bf16 out
// ---------------------------------------------------------------------------
__global__ __launch_bounds__(256) void ln_kernel(
    const float* __restrict__ x, const float* __restrict__ g,
    const float* __restrict__ b, float* __restrict__ outf,
    ushort_t* __restrict__ outb)
{
    const int t = blockIdx.x;
    const int tid = threadIdx.x;
    const int wave = tid >> 6, lane = tid & 63;
    const float4 v = ((const float4*)(x + (size_t)t * D_))[tid];

    float s = v.x + v.y + v.z + v.w;
#pragma unroll
    for (int off = 32; off; off >>= 1) s += __shfl_xor(s, off);
    __shared__ float red1[4];
    __shared__ float red2[4];
    if (lane == 0) red1[wave] = s;
    __syncthreads();
    const float mu = (red1[0] + red1[1] + red1[2] + red1[3]) * (1.0f / D_);

    const float dx = v.x - mu, dy = v.y - mu, dz = v.z - mu, dw = v.w - mu;
    float vs = dx * dx + dy * dy + dz * dz + dw * dw;
#pragma unroll
    for (int off = 32; off; off >>= 1) vs += __shfl_xor(vs, off);
    if (lane == 0) red2[wave] = vs;
    __syncthreads();
    const float var = (red2[0] + red2[1] + red2[2] + red2[3]) * (1.0f / D_);
    const float rs = 1.0f / sqrtf(var + 1e-5f);

    const float4 gg = ((const float4*)g)[tid];
    const float4 bb = ((const float4*)b)[tid];
    float4 o;
    o.x = dx * rs * gg.x + bb.x;
    o.y = dy * rs * gg.y + bb.y;
    o.z = dz * rs * gg.z + bb.z;
    o.w = dw * rs * gg.w + bb.w;
    if (outf) ((float4*)(outf + (size_t)t * D_))[tid] = o;
    if (outb) {
        ushort4 ob;
        ob.x = f2bf(o.x); ob.y = f2bf(o.y); ob.z = f2bf(o.z); ob.w = f2bf(o.w);
        ((ushort4*)(outb + (size_t)t * D_))[tid] = ob;
    }
}

// ---------------------------------------------------------------------------
// f32 SGEMM: tiles TM x 64, BK=16, 256 thr, (TM/16)x4 per thread.
// k-major LDS: As[k][m] broadcast reads, Bs[k][n] conflict-free.
// Optional dual store (C and C2).
// ---------------------------------------------------------------------------
template<int TM>
__global__ __launch_bounds__(256) void sgemm_kernel(
    const float* __restrict__ A, const float* __restrict__ B,
    const float* __restrict__ res, float* __restrict__ C,
    float* __restrict__ C2, int M, int N, int K)
{
    constexpr int RM  = TM / 16;      // rows per thread (8 or 4)
    constexpr int TPR = 256 / TM;     // threads per A row (2 or 4)
    constexpr int KF  = 16 / TPR;     // k-floats staged per thread (8 or 4)
    __shared__ float As[16][TM + 4];
    __shared__ float Bs[16][68];
    const int tid = threadIdx.x;
    const int m0 = blockIdx.y * TM, n0 = blockIdx.x * 64;
    const int tx = tid & 15, ty = tid >> 4;

    float acc[RM][4] = {};

    const int arow = tid / TPR;            // 0..TM-1
    const int akk  = (tid % TPR) * KF;     // 0..15 step KF
    const int bk = tid >> 4;               // 0..15
    const int bc = (tid & 15) * 4;         // 0..60

    const float* Ap = A + (size_t)(m0 + arow) * K + akk;
    const float* Bp = B + (size_t)bk * N + n0 + bc;

    for (int k0 = 0; k0 < K; k0 += 16) {
        float av[KF];
#pragma unroll
        for (int f = 0; f < KF / 4; f++) {
            const float4 t = *(const float4*)(Ap + k0 + f * 4);
            av[f * 4 + 0] = t.x; av[f * 4 + 1] = t.y;
            av[f * 4 + 2] = t.z; av[f * 4 + 3] = t.w;
        }
        const float4 bv = *(const float4*)(Bp + (size_t)k0 * N);
        __syncthreads();
#pragma unroll
        for (int i = 0; i < KF; i++) As[akk + i][arow] = av[i];
        *(float4*)&Bs[bk][bc] = bv;
        __syncthreads();
#pragma unroll
        for (int k = 0; k < 16; k++) {
            float a[RM];
#pragma unroll
            for (int f = 0; f < RM / 4; f++) {
                const float4 t = *(const float4*)&As[k][ty * RM + f * 4];
                a[f * 4 + 0] = t.x; a[f * 4 + 1] = t.y;
                a[f * 4 + 2] = t.z; a[f * 4 + 3] = t.w;
            }
            const float4 bb = *(const float4*)&Bs[k][tx * 4];
            const float bj[4] = {bb.x, bb.y, bb.z, bb.w};
#pragma unroll
            for (int i = 0; i < RM; i++)
#pragma unroll
                for (int j = 0; j < 4; j++)
                    acc[i][j] = fmaf(a[i], bj[j], acc[i][j]);
        }
    }

#pragma unroll
    for (int i = 0; i < RM; i++) {
        const int row = m0 + ty * RM + i;
        const size_t base = (size_t)row * N + n0 + tx * 4;
        float4 o;
        o.x = acc[i][0]; o.y = acc[i][1]; o.z = acc[i][2]; o.w = acc[i][3];
        if (res) {
            const float4 r0 = *(const float4*)(res + base);
            o.x += r0.x; o.y += r0.y; o.z += r0.z; o.w += r0.w;
        }
        *(float4*)(C + base) = o;
        if (C2) *(float4*)(C2 + base) = o;
    }
}

// ---------------------------------------------------------------------------
// Routed fused gate+up MoE GEMM: rows gathered from per-expert token lists.
// ---------------------------------------------------------------------------
__global__ __launch_bounds__(256) void gateup_idx_kernel(
    const ushort_t* __restrict__ A, const ushort_t* __restrict__ Bgu,
    const int* __restrict__ cnt, const int* __restrict__ tok,
    ushort_t* __restrict__ Hc)
{
    const int e = blockIdx.z;
    const int cntE = cnt[e];
    const int row0 = blockIdx.y * 128;
    if (row0 >= cntE) return;
    const int col0 = blockIdx.x * 128;
    const ushort_t* Bt = Bgu + (size_t)e * GU_ * D_;
    ushort_t* Hp = Hc + (size_t)e * T_ * HID_;

    __shared__ __align__(16) ushort_t As[128 * 32];
    __shared__ __align__(16) ushort_t Bs[128 * 32];
    const int tid = threadIdx.x, w = tid >> 6, lane = tid & 63;
    const int lr = lane >> 2, lc = (lane & 3) * 8;
    const int wm = (w >> 1) * 64, wn = (w & 1) * 64;
    const int lm = lane & 15, lq = lane >> 4;

    floatx4 acc[4][4] = {};

    int r0c = row0 + w * 16 + lr;  if (r0c > cntE - 1) r0c = cntE - 1;
    int r1c = row0 + 64 + w * 16 + lr; if (r1c > cntE - 1) r1c = cntE - 1;
    const ushort_t* Ap0 = A + (size_t)tok[e * T_ + r0c] * D_ + lc;
    const ushort_t* Ap1 = A + (size_t)tok[e * T_ + r1c] * D_ + lc;
    const ushort_t* Bp = Bt + (size_t)(col0 + w * 16 + lr) * D_ + lc;
    ushort_t* lA = As + w * 512;
    ushort_t* lB = Bs + w * 512;

    for (int k0 = 0; k0 < D_; k0 += 32) {
        __syncthreads();
        gl2lds16(Ap0 + k0, lA);
        gl2lds16(Ap1 + k0, lA + 2048);
        gl2lds16(Bp + k0, lB);
        gl2lds16(Bp + k0 + (size_t)64 * D_, lB + 2048);
        __syncthreads();
        bf16x8 a[4], b[4];
#pragma unroll
        for (int i = 0; i < 4; i++)
            a[i] = *(const bf16x8*)(As + (wm + i * 16 + lm) * 32 + lq * 8);
#pragma unroll
        for (int j = 0; j < 4; j++)
            b[j] = *(const bf16x8*)(Bs + (wn + j * 16 + lm) * 32 + lq * 8);
#pragma unroll
        for (int i = 0; i < 4; i++)
#pragma unroll
            for (int j = 0; j < 4; j++)
                acc[i][j] = __builtin_amdgcn_mfma_f32_16x16x32_bf16(a[i], b[j], acc[i][j], 0, 0, 0);
    }

    // epilogue: adjacent lanes hold (gate, up) for the same hidden unit
#pragma unroll
    for (int i = 0; i < 4; i++)
#pragma unroll
        for (int j = 0; j < 4; j++)
#pragma unroll
            for (int r = 0; r < 4; r++) {
                const float v = acc[i][j][r];
                const float vp = __shfl_xor(v, 1);
                const float g = (lm & 1) ? vp : v;
                const float u = (lm & 1) ? v : vp;
                const float h = g / (1.f + __expf(-g)) * u;
                if (!(lm & 1)) {
                    const int row = row0 + wm + i * 16 + lq * 4 + r;
                    const int col = col0 + wn + j * 16 + lm;    // even
                    Hp[(size_t)row * HID_ + (col >> 1)] = f2bf(h);
                }
            }
}

// ---------------------------------------------------------------------------
// Routed MoE down GEMM: out[tok[r]] += wt[r] * (Hc[e] @ wd[e]^T). grid (8,16,E)
// ---------------------------------------------------------------------------
__global__ __launch_bounds__(256) void down_idx_kernel(
    const ushort_t* __restrict__ Hc, const ushort_t* __restrict__ Wd,
    const int* __restrict__ cnt, const int* __restrict__ tok,
    const float* __restrict__ wt, float* __restrict__ out)
{
    const int e = blockIdx.z;
    const int cntE = cnt[e];
    const int row0 = blockIdx.y * 128;
    if (row0 >= cntE) return;
    const int col0 = blockIdx.x * 128;
    const ushort_t* A = Hc + (size_t)e * T_ * HID_;
    const ushort_t* Bt = Wd + (size_t)e * D_ * HID_;

    __shared__ __align__(16) ushort_t As[128 * 32];
    __shared__ __align__(16) ushort_t Bs[128 * 32];
    const int tid = threadIdx.x, w = tid >> 6, lane = tid & 63;
    const int lr = lane >> 2, lc = (lane & 3) * 8;
    const int wm = (w >> 1) * 64, wn = (w & 1) * 64;
    const int lm = lane & 15, lq = lane >> 4;

    floatx4 acc[4][4] = {};

    const ushort_t* Ap = A + (size_t)(row0 + w * 16 + lr) * HID_ + lc;
    const ushort_t* Bp = Bt + (size_t)(col0 + w * 16 + lr) * HID_ + lc;
    ushort_t* lA = As + w * 512;
    ushort_t* lB = Bs + w * 512;

    for (int k0 = 0; k0 < HID_; k0 += 32) {
        __syncthreads();
        gl2lds16(Ap + k0, lA);
        gl2lds16(Ap + k0 + (size_t)64 * HID_, lA + 2048);
        gl2lds16(Bp + k0, lB);
        gl2lds16(Bp + k0 + (size_t)64 * HID_, lB + 2048);
        __syncthreads();
        bf16x8 a[4], b[4];
#pragma unroll
        for (int i = 0; i < 4; i++)
            a[i] = *(const bf16x8*)(As + (wm + i * 16 + lm) * 32 + lq * 8);
#pragma unroll
        for (int j = 0; j < 4; j++)
            b[j] = *(const bf16x8*)(Bs + (wn + j * 16 + lm) * 32 + lq * 8);
#pragma unroll
        for (int i = 0; i < 4; i++)
#pragma unroll
            for (int j = 0; j < 4; j++)
                acc[i][j] = __builtin_amdgcn_mfma_f32_16x16x32_bf16(a[i], b[j], acc[i][j], 0, 0, 0);
    }

#pragma unroll
    for (int i = 0; i < 4; i++)
#pragma unroll
        for (int r = 0; r < 4; r++) {
            const int row = row0 + wm + i * 16 + lq * 4 + r;
            if (row < cntE) {
                const int t = tok[e * T_ + row];
                const float scale = wt[e * T_ + row];
#pragma unroll
                for (int j = 0; j < 4; j++) {
                    const int col = col0 + wn + j * 16 + lm;
                    atomicAdd(&out[(size_t)t * D_ + col], scale * acc[i][j][r]);
                }
            }
        }
}

// ---------------------------------------------------------------------------
// RoPE cos/sin tables (np f32 semantics via f64 pow/cos/sin)
// ---------------------------------------------------------------------------
__global__ __launch_bounds__(256) void rope_table_kernel(
    float* __restrict__ ctab, float* __restrict__ stab)
{
    const int i = blockIdx.x * 256 + threadIdx.x;   // S_*32
    if (i >= S_ * 32) return;
    const int s = i >> 5, p = i & 31;
    const double e = (double)(2 * p) / 64.0;
    const float pf = (float)pow(10000.0, e);
    const float invf = 1.0f / pf;
    const float fr = (float)s * invf;
    ctab[i] = (float)cos((double)fr);
    stab[i] = (float)sin((double)fr);
}

// ---------------------------------------------------------------------------
// RoPE in-place on qkv f32 (T x 3072): rotate q and k
// ---------------------------------------------------------------------------
__global__ __launch_bounds__(256) void rope_kernel(
    float* __restrict__ qkv, const float* __restrict__ ctab,
    const float* __restrict__ stab)
{
    const int n = blockIdx.x * 256 + threadIdx.x;     // T*H*32
    const int pair = n & 31;
    const int h = (n >> 5) & 15;
    const int t = n >> 9;
    const int s = t & (S_ - 1);
    const float c = ctab[s * 32 + pair];
    const float sn = stab[s * 32 + pair];
    const size_t base = (size_t)t * D3_ + h * HD_ + pair * 2;
    float x0 = qkv[base], x1 = qkv[base + 1];
    qkv[base]     = x0 * c - x1 * sn;
    qkv[base + 1] = x0 * sn + x1 * c;
    x0 = qkv[base + D_]; x1 = qkv[base + D_ + 1];
    qkv[base + D_]     = x0 * c - x1 * sn;
    qkv[base + D_ + 1] = x0 * sn + x1 * c;
}

// ---------------------------------------------------------------------------
// Flash-style causal attention, f32, precise expf.
// Vectorized LDS: kbuf rows strided 68 floats (b128 per-lane covers all 32
// banks per 8 lanes), qs/ps b128 broadcasts, vbuf 65-stride scalar (2-way,
// free). FMA chains keep the exact d/j-sequential order of the previous
// passing kernel -> bit-identical output. Heavy q-tiles dispatch first.
// ---------------------------------------------------------------------------
__global__ __launch_bounds__(256) void attn_kernel(
    const float* __restrict__ qkv, float* __restrict__ out)
{
    __shared__ __align__(16) float kbuf[64][68];
    __shared__ float vbuf[64][65];
    __shared__ __align__(16) float qs[32][64];
    __shared__ __align__(16) float ps[4][8][64];

    const int b = blockIdx.z, h = blockIdx.y;
    const int qt = (int)gridDim.x - 1 - (int)blockIdx.x;   // heavy first
    const int tid = threadIdx.x, wave = tid >> 6, lane = tid & 63;
    const int q0 = qt * 32;

    for (int i = tid; i < 32 * 64; i += 256) {
        const int qi = i >> 6, d = i & 63;
        const int t = b * S_ + q0 + qi;
        qs[qi][d] = qkv[(size_t)t * D3_ + h * HD_ + d];
    }

    float m[8], l[8], O[8];
#pragma unroll
    for (int qi = 0; qi < 8; qi++) { m[qi] = -INFINITY; l[qi] = 0.f; O[qi] = 0.f; }

    const int maxS = q0 + 31;
    for (int c0 = 0; c0 <= maxS; c0 += 64) {
        __syncthreads();   // protect kbuf/vbuf (and qs on first iter)
        for (int i = tid; i < 64 * 16; i += 256) {
            const int key = i >> 4, g = i & 15;
            const int t = b * S_ + c0 + key;
            const float4 kv = *(const float4*)(qkv + (size_t)t * D3_ + D_ + h * HD_ + g * 4);
            const float4 vv = *(const float4*)(qkv + (size_t)t * D3_ + 2 * D_ + h * HD_ + g * 4);
            *(float4*)&kbuf[key][g * 4] = kv;
            vbuf[key][g * 4 + 0] = vv.x; vbuf[key][g * 4 + 1] = vv.y;
            vbuf[key][g * 4 + 2] = vv.z; vbuf[key][g * 4 + 3] = vv.w;
        }
        __syncthreads();

        const int kglob = c0 + lane;
        float sc[8];
#pragma unroll
        for (int qi = 0; qi < 8; qi++) sc[qi] = 0.f;
#pragma unroll 4
        for (int g = 0; g < 16; g++) {
            const float4 kv = *(const float4*)&kbuf[lane][g * 4];
#pragma unroll
            for (int qi = 0; qi < 8; qi++) {
                const float4 qv = *(const float4*)&qs[wave * 8 + qi][g * 4];
                float s = sc[qi];
                s = fmaf(qv.x, kv.x, s);
                s = fmaf(qv.y, kv.y, s);
                s = fmaf(qv.z, kv.z, s);
                s = fmaf(qv.w, kv.w, s);
                sc[qi] = s;
            }
        }
#pragma unroll
        for (int qi = 0; qi < 8; qi++) {
            const int s = q0 + wave * 8 + qi;
            float v = (kglob <= s) ? sc[qi] * 0.125f : -INFINITY;
            float cmax = v;
#pragma unroll
            for (int off = 32; off; off >>= 1) cmax = fmaxf(cmax, __shfl_xor(cmax, off));
            const float mnew = fmaxf(m[qi], cmax);
            const float alpha = expf(m[qi] - mnew);
            const float p = (v == -INFINITY) ? 0.f : expf(v - mnew);
            float psum = p;
#pragma unroll
            for (int off = 32; off; off >>= 1) psum += __shfl_xor(psum, off);
            l[qi] = l[qi] * alpha + psum;
            m[qi] = mnew;
            ps[wave][qi][lane] = p;
            sc[qi] = alpha;                 // stash (uniform across lanes)
        }
#pragma unroll
        for (int qi = 0; qi < 8; qi++) O[qi] *= sc[qi];
#pragma unroll 4
        for (int g = 0; g < 16; g++) {
            const float v0 = vbuf[g * 4 + 0][lane];
            const float v1 = vbuf[g * 4 + 1][lane];
            const float v2 = vbuf[g * 4 + 2][lane];
            const float v3 = vbuf[g * 4 + 3][lane];
#pragma unroll
            for (int qi = 0; qi < 8; qi++) {
                const float4 p4 = *(const float4*)&ps[wave][qi][g * 4];
                float o = O[qi];
                o = fmaf(p4.x, v0, o);
                o = fmaf(p4.y, v1, o);
                o = fmaf(p4.z, v2, o);
                o = fmaf(p4.w, v3, o);
                O[qi] = o;
            }
        }
    }

#pragma unroll
    for (int qi = 0; qi < 8; qi++) {
        const int t = b * S_ + q0 + wave * 8 + qi;
        out[(size_t)t * D_ + h * HD_ + lane] = O[qi] / l[qi];
    }
}

// ---------------------------------------------------------------------------
// Gating + routing. bf16-rounded logits, top-2 lowest-index tie-break;
// scatters (token, weight) into per-expert lists; probs -> buffer.
// ---------------------------------------------------------------------------
__global__ __launch_bounds__(64) void gate_kernel(
    const ushort_t* __restrict__ xn2, const float* __restrict__ gate_w,
    int* __restrict__ cnt, int* __restrict__ tok, float* __restrict__ wt,
    float* __restrict__ probs)
{
    const int t = blockIdx.x;
    const int lane = threadIdx.x;
    float acc[8] = {0, 0, 0, 0, 0, 0, 0, 0};
    for (int d = lane; d < D_; d += 64) {
        const float xv = bf2f(xn2[(size_t)t * D_ + d]);
        const float4 g0 = ((const float4*)(gate_w + d * 8))[0];
        const float4 g1 = ((const float4*)(gate_w + d * 8))[1];
        acc[0] = fmaf(xv, bf2f(f2bf(g0.x)), acc[0]);
        acc[1] = fmaf(xv, bf2f(f2bf(g0.y)), acc[1]);
        acc[2] = fmaf(xv, bf2f(f2bf(g0.z)), acc[2]);
        acc[3] = fmaf(xv, bf2f(f2bf(g0.w)), acc[3]);
        acc[4] = fmaf(xv, bf2f(f2bf(g1.x)), acc[4]);
        acc[5] = fmaf(xv, bf2f(f2bf(g1.y)), acc[5]);
        acc[6] = fmaf(xv, bf2f(f2bf(g1.z)), acc[6]);
        acc[7] = fmaf(xv, bf2f(f2bf(g1.w)), acc[7]);
    }
#pragma unroll
    for (int e = 0; e < 8; e++) {
#pragma unroll
        for (int off = 32; off; off >>= 1) acc[e] += __shfl_xor(acc[e], off);
        acc[e] = bf2f(f2bf(acc[e]));   // bf16 result of the bf16 matmul
    }

    if (lane == 0) {
        int i1 = 0;
        for (int e = 1; e < 8; e++) if (acc[e] > acc[i1]) i1 = e;
        int i2 = (i1 == 0) ? 1 : 0;
        for (int e = 0; e < 8; e++) if (e != i1 && acc[e] > acc[i2]) i2 = e;
        const float e2 = expf(acc[i2] - acc[i1]);
        const float w1 = 1.f / (1.f + e2);
        const float w2 = e2 * w1;
        const int p1 = atomicAdd(&cnt[i1], 1);
        tok[i1 * T_ + p1] = t; wt[i1 * T_ + p1] = w1;
        const int p2 = atomicAdd(&cnt[i2], 1);
        tok[i2 * T_ + p2] = t; wt[i2 * T_ + p2] = w2;
        const float mx = acc[i1];
        float se = 0.f, pe[8];
        for (int e = 0; e < 8; e++) { pe[e] = expf(acc[e] - mx); se += pe[e]; }
        const float inv = 1.f / se;
        for (int e = 0; e < 8; e++) probs[t * 8 + e] = pe[e] * inv;
    }
}

__global__ void zero_route_kernel(int* __restrict__ cnt)
{
    if (threadIdx.x < 8) cnt[threadIdx.x] = 0;
}

// ---------------------------------------------------------------------------
// dist = probs.mean(0); lb = E * sum(dist^2); writes out tail.
// ---------------------------------------------------------------------------
__global__ __launch_bounds__(256) void reduce_dist_kernel(
    const float* __restrict__ probs, float* __restrict__ out)
{
    __shared__ float part[256];
    __shared__ float dist8[8];
    const int tid = threadIdx.x;
    const int e = tid & 7, chunk = tid >> 3;   // 32 chunks
    float s = 0.f;
    for (int t = chunk; t < T_; t += 32) s += probs[t * 8 + e];
    part[tid] = s;
    __syncthreads();
    if (tid < 8) {
        float tot = 0.f;
        for (int c = 0; c < 32; c++) tot += part[c * 8 + tid];
        const float dv = tot * (1.0f / T_);
        dist8[tid] = dv;
        out[(size_t)T_ * D_ + 1 + tid] = dv;
    }
    __syncthreads();
    if (tid == 0) {
        float s2 = 0.f;
        for (int k = 0; k < 8; k++) s2 += dist8[k] * dist8[k];
        out[(size_t)T_ * D_] = (float)E_ * s2;
    }
}

// ---------------------------------------------------------------------------
// Launch
// ---------------------------------------------------------------------------
extern "C" void kernel_launch(void* const* d_in, const int* in_sizes, int n_in,
                              void* d_out, int out_size, void* d_ws, size_t ws_size,
                              hipStream_t stream)
{
    const float* x      = (const float*)d_in[0];
    const float* ln1_g  = (const float*)d_in[1];
    const float* ln1_b  = (const float*)d_in[2];
    const float* ln2_g  = (const float*)d_in[3];
    const float* ln2_b  = (const float*)d_in[4];
    const float* w_qkv  = (const float*)d_in[5];
    const float* w_o    = (const float*)d_in[6];
    const float* gate_w = (const float*)d_in[7];
    const float* w_gate = (const float*)d_in[8];
    const float* w_up   = (const float*)d_in[9];
    const float* w_down = (const float*)d_in[10];
    float* out = (float*)d_out;

    char* ws = (char*)d_ws;
    size_t off = 0;
    auto alloc = [&](size_t bytes) { size_t o = off; off += (bytes + 255) & ~(size_t)255; return o; };
    // persistent-through-MoE region
    ushort_t* wguT  = (ushort_t*)(ws + alloc((size_t)E_ * GU_ * D_ * 2));   // 58.7 MB
    ushort_t* wdT   = (ushort_t*)(ws + alloc((size_t)E_ * D_ * HID_ * 2));  // 29.4 MB
    float*    xn    = (float*)   (ws + alloc((size_t)T_ * D_ * 4));
    ushort_t* xn2   = (ushort_t*)(ws + alloc((size_t)T_ * D_ * 2));
    int*      cnt   = (int*)     (ws + alloc(64));
    int*      tok   = (int*)     (ws + alloc((size_t)E_ * T_ * 4));
    float*    wt    = (float*)   (ws + alloc((size_t)E_ * T_ * 4));
    float*    probs = (float*)   (ws + alloc((size_t)T_ * E_ * 4));
    float*    ctab  = (float*)   (ws + alloc((size_t)S_ * 32 * 4));
    float*    stab  = (float*)   (ws + alloc((size_t)S_ * 32 * 4));
    // scratch region: qkv/attnO/x1 dead before MoE; Hc aliases
    const size_t scratch0 = alloc((size_t)E_ * T_ * HID_ * 2);
    float*    qkv   = (float*)   (ws + scratch0);
    float*    attnO = (float*)   (ws + scratch0 + (size_t)T_ * D3_ * 4);
    float*    x1    = (float*)   (ws + scratch0 + (size_t)T_ * D3_ * 4 + (size_t)T_ * D_ * 4);
    ushort_t* Hc    = (ushort_t*)(ws + scratch0);
    (void)ws_size; (void)in_sizes; (void)n_in; (void)out_size;

    // weight transposes -> bf16 (N x K); gate/up interleaved into wguT
    hipLaunchKernelGGL(transpose_bf16_kernel, dim3(HID_ / 32, D_ / 32, E_), dim3(256), 0, stream,
                       w_gate, wguT, D_, HID_, 2, 0, (long)GU_ * D_);
    hipLaunchKernelGGL(transpose_bf16_kernel, dim3(HID_ / 32, D_ / 32, E_), dim3(256), 0, stream,
                       w_up, wguT, D_, HID_, 2, 1, (long)GU_ * D_);
    hipLaunchKernelGGL(transpose_bf16_kernel, dim3(D_ / 32, HID_ / 32, E_), dim3(256), 0, stream,
                       w_down, wdT, HID_, D_, 1, 0, (long)D_ * HID_);

    // RoPE tables
    hipLaunchKernelGGL(rope_table_kernel, dim3((S_ * 32 + 255) / 256), dim3(256), 0, stream,
                       ctab, stab);

    // LN1 (f32)
    hipLaunchKernelGGL(ln_kernel, dim3(T_), dim3(256), 0, stream,
                       x, ln1_g, ln1_b, xn, (ushort_t*)nullptr);

    // QKV f32 SGEMM: 128x64 tiles -> 48x16 = 768 blocks
    hipLaunchKernelGGL((sgemm_kernel<128>), dim3(D3_ / 64, T_ / 128), dim3(256), 0, stream,
                       xn, w_qkv, (const float*)nullptr, qkv, (float*)nullptr, T_, D3_, D_);

    // RoPE
    hipLaunchKernelGGL(rope_kernel, dim3(T_ * H_ * 32 / 256), dim3(256), 0, stream,
                       qkv, ctab, stab);

    // attention
    hipLaunchKernelGGL(attn_kernel, dim3(S_ / 32, H_, B_), dim3(256), 0, stream, qkv, attnO);

    // W_O SGEMM + residual -> x1 AND out (down_idx accumulates on out)
    hipLaunchKernelGGL((sgemm_kernel<64>), dim3(D_ / 64, T_ / 64), dim3(256), 0, stream,
                       attnO, w_o, x, x1, out, T_, D_, D_);

    // LN2 (bf16)
    hipLaunchKernelGGL(ln_kernel, dim3(T_), dim3(256), 0, stream,
                       x1, ln2_g, ln2_b, (float*)nullptr, xn2);

    // gating + routing + aux outputs
    hipLaunchKernelGGL(zero_route_kernel, dim3(1), dim3(64), 0, stream, cnt);
    hipLaunchKernelGGL(gate_kernel, dim3(T_), dim3(64), 0, stream,
                       xn2, gate_w, cnt, tok, wt, probs);
    hipLaunchKernelGGL(reduce_dist_kernel, dim3(1), dim3(256), 0, stream, probs, out);

    // MoE routed: fused gate+up (+silu), then weighted down accumulation
    hipLaunchKernelGGL(gateup_idx_kernel, dim3(GU_ / 128, T_ / 128, E_), dim3(256), 0, stream,
                       xn2, wguT, cnt, tok, Hc);
    hipLaunchKernelGGL(down_idx_kernel, dim3(D_ / 128, T_ / 128, E_), dim3(256), 0, stream,
                       Hc, wdT, cnt, tok, wt, out);
}

// Round 6
// 841.803 us; speedup vs baseline: 1.0185x; 1.0185x over previous
//
#include <hip/hip_runtime.h>
#include <hip/hip_bf16.h>
#include <math.h>

// ---------------------------------------------------------------------------
// Shapes (fixed by the problem)
// ---------------------------------------------------------------------------
#define B_    4
#define S_    512
#define D_    1024
#define T_    2048          // B*S tokens
#define H_    16
#define HD_   64
#define E_    8
#define HID_  1792
#define D3_   3072
#define GU_   (2 * HID_)    // 3584 interleaved gate/up columns
#define NPART_ 72           // partial chunks per (b,h): sum_{qt<16} (qt/2+1)

typedef unsigned short ushort_t;
typedef __bf16 bf16x8 __attribute__((ext_vector_type(8)));
typedef float  floatx4 __attribute__((ext_vector_type(4)));

__constant__ int kPrefix[16] = {0,1,2,4,6,9,12,16,20,25,30,36,42,49,56,64};

__device__ inline float bf2f(ushort_t u) {
    return __uint_as_float(((unsigned)u) << 16);
}
__device__ inline ushort_t f2bf(float f) {
    __hip_bfloat16 h = __float2bfloat16(f);
    return __builtin_bit_cast(ushort_t, h);
}

// async 16B/lane global->LDS; lds dest wave-uniform base (+lane*16 by HW)
__device__ __forceinline__ void gl2lds16(const ushort_t* g, ushort_t* l) {
    __builtin_amdgcn_global_load_lds(
        (const __attribute__((address_space(1))) void*)g,
        (__attribute__((address_space(3))) void*)l, 16, 0, 0);
}

// ---------------------------------------------------------------------------
// Transpose + fp32->bf16: in (z,R,C) f32 -> out[z*outEstride + (c*mul+add)*R + r]
// ---------------------------------------------------------------------------
__global__ __launch_bounds__(256) void transpose_bf16_kernel(
    const float* __restrict__ in, ushort_t* __restrict__ out,
    int R, int C, int mul, int add, long outEstride)
{
    __shared__ float tile[32][33];
    const int bx = blockIdx.x * 32;           // c
    const int by = blockIdx.y * 32;           // r
    const size_t iofs = (size_t)blockIdx.z * R * C;
    const size_t oofs = (size_t)blockIdx.z * outEstride;
    const int tx = threadIdx.x & 31;
    const int ty = threadIdx.x >> 5;          // 0..7
#pragma unroll
    for (int i = 0; i < 4; i++) {
        int r = by + ty + i * 8;
        tile[ty + i * 8][tx] = in[iofs + (size_t)r * C + bx + tx];
    }
    __syncthreads();
#pragma unroll
    for (int i = 0; i < 4; i++) {
        int c = bx + ty + i * 8;
        out[oofs + (size_t)(c * mul + add) * R + by + tx] = f2bf(tile[tx][ty + i * 8]);
    }
}

// ---------------------------------------------------------------------------
// LayerNorm: x (rows x 1024) f32 -> f32 out and/or bf16 out
// ---------------------------------------------------------------------------
__global__ __launch_bounds__(256) void ln_kernel(
    const float* __restrict__ x, const float* __restrict__ g,
    const float* __restrict__ b, float* __restrict__ outf,
    ushort_t* __restrict__ outb)
{
    const int t = blockIdx.x;
    const int tid = threadIdx.x;
    const int wave = tid >> 6, lane = tid & 63;
    const float4 v = ((const float4*)(x + (size_t)t * D_))[tid];

    float s = v.x + v.y + v.z + v.w;
#pragma unroll
    for (int off = 32; off; off >>= 1) s += __shfl_xor(s, off);
    __shared__ float red1[4];
    __shared__ float red2[4];
    if (lane == 0) red1[wave] = s;
    __syncthreads();
    const float mu = (red1[0] + red1[1] + red1[2] + red1[3]) * (1.0f / D_);

    const float dx = v.x - mu, dy = v.y - mu, dz = v.z - mu, dw = v.w - mu;
    float vs = dx * dx + dy * dy + dz * dz + dw * dw;
#pragma unroll
    for (int off = 32; off; off >>= 1) vs += __shfl_xor(vs, off);
    if (lane == 0) red2[wave] = vs;
    __syncthreads();
    const float var = (red2[0] + red2[1] + red2[2] + red2[3]) * (1.0f / D_);
    const float rs = 1.0f / sqrtf(var + 1e-5f);

    const float4 gg = ((const float4*)g)[tid];
    const float4 bb = ((const float4*)b)[tid];
    float4 o;
    o.x = dx * rs * gg.x + bb.x;
    o.y = dy * rs * gg.y + bb.y;
    o.z = dz * rs * gg.z + bb.z;
    o.w = dw * rs * gg.w + bb.w;
    if (outf) ((float4*)(outf + (size_t)t * D_))[tid] = o;
    if (outb) {
        ushort4 ob;
        ob.x = f2bf(o.x); ob.y = f2bf(o.y); ob.z = f2bf(o.z); ob.w = f2bf(o.w);
        ((ushort4*)(outb + (size_t)t * D_))[tid] = ob;
    }
}

// ---------------------------------------------------------------------------
// f32 SGEMM: tiles TM x 64, BK=16, 256 thr, (TM/16)x4 per thread.
// ---------------------------------------------------------------------------
template<int TM>
__global__ __launch_bounds__(256) void sgemm_kernel(
    const float* __restrict__ A, const float* __restrict__ B,
    const float* __restrict__ res, float* __restrict__ C,
    float* __restrict__ C2, int M, int N, int K)
{
    constexpr int RM  = TM / 16;      // rows per thread (8 or 4)
    constexpr int TPR = 256 / TM;     // threads per A row (2 or 4)
    constexpr int KF  = 16 / TPR;     // k-floats staged per thread (8 or 4)
    __shared__ float As[16][TM + 4];
    __shared__ float Bs[16][68];
    const int tid = threadIdx.x;
    const int m0 = blockIdx.y * TM, n0 = blockIdx.x * 64;
    const int tx = tid & 15, ty = tid >> 4;

    float acc[RM][4] = {};

    const int arow = tid / TPR;            // 0..TM-1
    const int akk  = (tid % TPR) * KF;     // 0..15 step KF
    const int bk = tid >> 4;               // 0..15
    const int bc = (tid & 15) * 4;         // 0..60

    const float* Ap = A + (size_t)(m0 + arow) * K + akk;
    const float* Bp = B + (size_t)bk * N + n0 + bc;

    for (int k0 = 0; k0 < K; k0 += 16) {
        float av[KF];
#pragma unroll
        for (int f = 0; f < KF / 4; f++) {
            const float4 t = *(const float4*)(Ap + k0 + f * 4);
            av[f * 4 + 0] = t.x; av[f * 4 + 1] = t.y;
            av[f * 4 + 2] = t.z; av[f * 4 + 3] = t.w;
        }
        const float4 bv = *(const float4*)(Bp + (size_t)k0 * N);
        __syncthreads();
#pragma unroll
        for (int i = 0; i < KF; i++) As[akk + i][arow] = av[i];
        *(float4*)&Bs[bk][bc] = bv;
        __syncthreads();
#pragma unroll
        for (int k = 0; k < 16; k++) {
            float a[RM];
#pragma unroll
            for (int f = 0; f < RM / 4; f++) {
                const float4 t = *(const float4*)&As[k][ty * RM + f * 4];
                a[f * 4 + 0] = t.x; a[f * 4 + 1] = t.y;
                a[f * 4 + 2] = t.z; a[f * 4 + 3] = t.w;
            }
            const float4 bb = *(const float4*)&Bs[k][tx * 4];
            const float bj[4] = {bb.x, bb.y, bb.z, bb.w};
#pragma unroll
            for (int i = 0; i < RM; i++)
#pragma unroll
                for (int j = 0; j < 4; j++)
                    acc[i][j] = fmaf(a[i], bj[j], acc[i][j]);
        }
    }

#pragma unroll
    for (int i = 0; i < RM; i++) {
        const int row = m0 + ty * RM + i;
        const size_t base = (size_t)row * N + n0 + tx * 4;
        float4 o;
        o.x = acc[i][0]; o.y = acc[i][1]; o.z = acc[i][2]; o.w = acc[i][3];
        if (res) {
            const float4 r0 = *(const float4*)(res + base);
            o.x += r0.x; o.y += r0.y; o.z += r0.z; o.w += r0.w;
        }
        *(float4*)(C + base) = o;
        if (C2) *(float4*)(C2 + base) = o;
    }
}

// ---------------------------------------------------------------------------
// Routed fused gate+up MoE GEMM: rows gathered from per-expert token lists.
// ---------------------------------------------------------------------------
__global__ __launch_bounds__(256) void gateup_idx_kernel(
    const ushort_t* __restrict__ A, const ushort_t* __restrict__ Bgu,
    const int* __restrict__ cnt, const int* __restrict__ tok,
    ushort_t* __restrict__ Hc)
{
    const int e = blockIdx.z;
    const int cntE = cnt[e];
    const int row0 = blockIdx.y * 128;
    if (row0 >= cntE) return;
    const int col0 = blockIdx.x * 128;
    const ushort_t* Bt = Bgu + (size_t)e * GU_ * D_;
    ushort_t* Hp = Hc + (size_t)e * T_ * HID_;

    __shared__ __align__(16) ushort_t As[128 * 32];
    __shared__ __align__(16) ushort_t Bs[128 * 32];
    const int tid = threadIdx.x, w = tid >> 6, lane = tid & 63;
    const int lr = lane >> 2, lc = (lane & 3) * 8;
    const int wm = (w >> 1) * 64, wn = (w & 1) * 64;
    const int lm = lane & 15, lq = lane >> 4;

    floatx4 acc[4][4] = {};

    int r0c = row0 + w * 16 + lr;  if (r0c > cntE - 1) r0c = cntE - 1;
    int r1c = row0 + 64 + w * 16 + lr; if (r1c > cntE - 1) r1c = cntE - 1;
    const ushort_t* Ap0 = A + (size_t)tok[e * T_ + r0c] * D_ + lc;
    const ushort_t* Ap1 = A + (size_t)tok[e * T_ + r1c] * D_ + lc;
    const ushort_t* Bp = Bt + (size_t)(col0 + w * 16 + lr) * D_ + lc;
    ushort_t* lA = As + w * 512;
    ushort_t* lB = Bs + w * 512;

    for (int k0 = 0; k0 < D_; k0 += 32) {
        __syncthreads();
        gl2lds16(Ap0 + k0, lA);
        gl2lds16(Ap1 + k0, lA + 2048);
        gl2lds16(Bp + k0, lB);
        gl2lds16(Bp + k0 + (size_t)64 * D_, lB + 2048);
        __syncthreads();
        bf16x8 a[4], b[4];
#pragma unroll
        for (int i = 0; i < 4; i++)
            a[i] = *(const bf16x8*)(As + (wm + i * 16 + lm) * 32 + lq * 8);
#pragma unroll
        for (int j = 0; j < 4; j++)
            b[j] = *(const bf16x8*)(Bs + (wn + j * 16 + lm) * 32 + lq * 8);
#pragma unroll
        for (int i = 0; i < 4; i++)
#pragma unroll
            for (int j = 0; j < 4; j++)
                acc[i][j] = __builtin_amdgcn_mfma_f32_16x16x32_bf16(a[i], b[j], acc[i][j], 0, 0, 0);
    }

    // epilogue: adjacent lanes hold (gate, up) for the same hidden unit
#pragma unroll
    for (int i = 0; i < 4; i++)
#pragma unroll
        for (int j = 0; j < 4; j++)
#pragma unroll
            for (int r = 0; r < 4; r++) {
                const float v = acc[i][j][r];
                const float vp = __shfl_xor(v, 1);
                const float g = (lm & 1) ? vp : v;
                const float u = (lm & 1) ? v : vp;
                const float h = g / (1.f + __expf(-g)) * u;
                if (!(lm & 1)) {
                    const int row = row0 + wm + i * 16 + lq * 4 + r;
                    const int col = col0 + wn + j * 16 + lm;    // even
                    Hp[(size_t)row * HID_ + (col >> 1)] = f2bf(h);
                }
            }
}

// ---------------------------------------------------------------------------
// Routed MoE down GEMM: out[tok[r]] += wt[r] * (Hc[e] @ wd[e]^T). grid (8,16,E)
// ---------------------------------------------------------------------------
__global__ __launch_bounds__(256) void down_idx_kernel(
    const ushort_t* __restrict__ Hc, const ushort_t* __restrict__ Wd,
    const int* __restrict__ cnt, const int* __restrict__ tok,
    const float* __restrict__ wt, float* __restrict__ out)
{
    const int e = blockIdx.z;
    const int cntE = cnt[e];
    const int row0 = blockIdx.y * 128;
    if (row0 >= cntE) return;
    const int col0 = blockIdx.x * 128;
    const ushort_t* A = Hc + (size_t)e * T_ * HID_;
    const ushort_t* Bt = Wd + (size_t)e * D_ * HID_;

    __shared__ __align__(16) ushort_t As[128 * 32];
    __shared__ __align__(16) ushort_t Bs[128 * 32];
    const int tid = threadIdx.x, w = tid >> 6, lane = tid & 63;
    const int lr = lane >> 2, lc = (lane & 3) * 8;
    const int wm = (w >> 1) * 64, wn = (w & 1) * 64;
    const int lm = lane & 15, lq = lane >> 4;

    floatx4 acc[4][4] = {};

    const ushort_t* Ap = A + (size_t)(row0 + w * 16 + lr) * HID_ + lc;
    const ushort_t* Bp = Bt + (size_t)(col0 + w * 16 + lr) * HID_ + lc;
    ushort_t* lA = As + w * 512;
    ushort_t* lB = Bs + w * 512;

    for (int k0 = 0; k0 < HID_; k0 += 32) {
        __syncthreads();
        gl2lds16(Ap + k0, lA);
        gl2lds16(Ap + k0 + (size_t)64 * HID_, lA + 2048);
        gl2lds16(Bp + k0, lB);
        gl2lds16(Bp + k0 + (size_t)64 * HID_, lB + 2048);
        __syncthreads();
        bf16x8 a[4], b[4];
#pragma unroll
        for (int i = 0; i < 4; i++)
            a[i] = *(const bf16x8*)(As + (wm + i * 16 + lm) * 32 + lq * 8);
#pragma unroll
        for (int j = 0; j < 4; j++)
            b[j] = *(const bf16x8*)(Bs + (wn + j * 16 + lm) * 32 + lq * 8);
#pragma unroll
        for (int i = 0; i < 4; i++)
#pragma unroll
            for (int j = 0; j < 4; j++)
                acc[i][j] = __builtin_amdgcn_mfma_f32_16x16x32_bf16(a[i], b[j], acc[i][j], 0, 0, 0);
    }

#pragma unroll
    for (int i = 0; i < 4; i++)
#pragma unroll
        for (int r = 0; r < 4; r++) {
            const int row = row0 + wm + i * 16 + lq * 4 + r;
            if (row < cntE) {
                const int t = tok[e * T_ + row];
                const float scale = wt[e * T_ + row];
#pragma unroll
                for (int j = 0; j < 4; j++) {
                    const int col = col0 + wn + j * 16 + lm;
                    atomicAdd(&out[(size_t)t * D_ + col], scale * acc[i][j][r]);
                }
            }
        }
}

// ---------------------------------------------------------------------------
// RoPE cos/sin tables (np f32 semantics via f64 pow/cos/sin)
// ---------------------------------------------------------------------------
__global__ __launch_bounds__(256) void rope_table_kernel(
    float* __restrict__ ctab, float* __restrict__ stab)
{
    const int i = blockIdx.x * 256 + threadIdx.x;   // S_*32
    if (i >= S_ * 32) return;
    const int s = i >> 5, p = i & 31;
    const double e = (double)(2 * p) / 64.0;
    const float pf = (float)pow(10000.0, e);
    const float invf = 1.0f / pf;
    const float fr = (float)s * invf;
    ctab[i] = (float)cos((double)fr);
    stab[i] = (float)sin((double)fr);
}

// ---------------------------------------------------------------------------
// RoPE in-place on qkv f32 (T x 3072): rotate q and k
// ---------------------------------------------------------------------------
__global__ __launch_bounds__(256) void rope_kernel(
    float* __restrict__ qkv, const float* __restrict__ ctab,
    const float* __restrict__ stab)
{
    const int n = blockIdx.x * 256 + threadIdx.x;     // T*H*32
    const int pair = n & 31;
    const int h = (n >> 5) & 15;
    const int t = n >> 9;
    const int s = t & (S_ - 1);
    const float c = ctab[s * 32 + pair];
    const float sn = stab[s * 32 + pair];
    const size_t base = (size_t)t * D3_ + h * HD_ + pair * 2;
    float x0 = qkv[base], x1 = qkv[base + 1];
    qkv[base]     = x0 * c - x1 * sn;
    qkv[base + 1] = x0 * sn + x1 * c;
    x0 = qkv[base + D_]; x1 = qkv[base + D_ + 1];
    qkv[base + D_]     = x0 * c - x1 * sn;
    qkv[base + D_ + 1] = x0 * sn + x1 * c;
}

// ---------------------------------------------------------------------------
// Split-K flash attention, pass 1: one (q-tile, key-chunk) partial per block.
// grid (8 kc, 16 qt, 64 bh); blocks with kc > qt/2 exit. Per block: stage
// Q(32x64), K,V(64x64) once, one barrier, per-wave 8 q-rows: scores, chunk
// softmax (m=chunk max, l=chunk sum, unnormalized O), write O_part + (m,l).
// FMA chain order per chunk identical to the sequential version.
// ---------------------------------------------------------------------------
__global__ __launch_bounds__(256) void attn_part_kernel(
    const float* __restrict__ qkv, float* __restrict__ Opart,
    float* __restrict__ Ml)
{
    const int qt = blockIdx.y;
    const int kc = blockIdx.x;
    if (kc > (qt >> 1)) return;
    const int bh = blockIdx.z;                 // b*16+h
    const int b = bh >> 4, h = bh & 15;
    const int q0 = qt * 32;
    const int c0 = kc * 64;
    const int pidx = bh * NPART_ + kPrefix[qt] + kc;

    __shared__ __align__(16) float kbuf[64][68];
    __shared__ __align__(16) float vbuf[64][68];
    __shared__ __align__(16) float qs[32][68];
    __shared__ __align__(16) float ps[4][8][68];

    const int tid = threadIdx.x, wave = tid >> 6, lane = tid & 63;

    for (int i = tid; i < 32 * 16; i += 256) {
        const int qi = i >> 4, g = i & 15;
        const int t = b * S_ + q0 + qi;
        *(float4*)&qs[qi][g * 4] =
            *(const float4*)(qkv + (size_t)t * D3_ + h * HD_ + g * 4);
    }
    for (int i = tid; i < 64 * 16; i += 256) {
        const int key = i >> 4, g = i & 15;
        const int t = b * S_ + c0 + key;
        *(float4*)&kbuf[key][g * 4] =
            *(const float4*)(qkv + (size_t)t * D3_ + D_ + h * HD_ + g * 4);
        *(float4*)&vbuf[key][g * 4] =
            *(const float4*)(qkv + (size_t)t * D3_ + 2 * D_ + h * HD_ + g * 4);
    }
    __syncthreads();

    const int kglob = c0 + lane;
    float sc[8];
#pragma unroll
    for (int qi = 0; qi < 8; qi++) sc[qi] = 0.f;
#pragma unroll 4
    for (int g = 0; g < 16; g++) {
        const float4 kv = *(const float4*)&kbuf[lane][g * 4];
#pragma unroll
        for (int qi = 0; qi < 8; qi++) {
            const float4 qv = *(const float4*)&qs[wave * 8 + qi][g * 4];
            float s = sc[qi];
            s = fmaf(qv.x, kv.x, s);
            s = fmaf(qv.y, kv.y, s);
            s = fmaf(qv.z, kv.z, s);
            s = fmaf(qv.w, kv.w, s);
            sc[qi] = s;
        }
    }
#pragma unroll
    for (int qi = 0; qi < 8; qi++) {
        const int s = q0 + wave * 8 + qi;
        float v = (kglob <= s) ? sc[qi] * 0.125f : -INFINITY;
        float cmax = v;
#pragma unroll
        for (int off = 32; off; off >>= 1) cmax = fmaxf(cmax, __shfl_xor(cmax, off));
        const float p = (v == -INFINITY) ? 0.f : expf(v - cmax);
        float psum = p;
#pragma unroll
        for (int off = 32; off; off >>= 1) psum += __shfl_xor(psum, off);
        ps[wave][qi][lane] = p;
        if (lane == 0) {
            Ml[(size_t)pidx * 64 + wave * 8 + qi] = cmax;
            Ml[(size_t)pidx * 64 + 32 + wave * 8 + qi] = psum;
        }
    }

    float O[8];
#pragma unroll
    for (int qi = 0; qi < 8; qi++) O[qi] = 0.f;
#pragma unroll 4
    for (int g = 0; g < 16; g++) {
        const float v0 = vbuf[g * 4 + 0][lane];
        const float v1 = vbuf[g * 4 + 1][lane];
        const float v2 = vbuf[g * 4 + 2][lane];
        const float v3 = vbuf[g * 4 + 3][lane];
#pragma unroll
        for (int qi = 0; qi < 8; qi++) {
            const float4 p4 = *(const float4*)&ps[wave][qi][g * 4];
            float o = O[qi];
            o = fmaf(p4.x, v0, o);
            o = fmaf(p4.y, v1, o);
            o = fmaf(p4.z, v2, o);
            o = fmaf(p4.w, v3, o);
            O[qi] = o;
        }
    }
#pragma unroll
    for (int qi = 0; qi < 8; qi++)
        Opart[((size_t)pidx * 32 + wave * 8 + qi) * 64 + lane] = O[qi];
}

// ---------------------------------------------------------------------------
// Split-K flash attention, pass 2: combine <=8 partials per (bh,qt).
// grid (16 qt, 64 bh), 256 thr: thread = (qrow, 8 dims).
// ---------------------------------------------------------------------------
__global__ __launch_bounds__(256) void attn_combine_kernel(
    const float* __restrict__ Opart, const float* __restrict__ Ml,
    float* __restrict__ out)
{
    const int qt = blockIdx.x, bh = blockIdx.y;
    const int b = bh >> 4, h = bh & 15;
    const int nchunk = (qt >> 1) + 1;
    const int base = bh * NPART_ + kPrefix[qt];
    const int tid = threadIdx.x;
    const int qrow = tid >> 3;            // 0..31
    const int d0 = (tid & 7) * 8;         // 0..56

    float M = -INFINITY;
    for (int c = 0; c < nchunk; c++)
        M = fmaxf(M, Ml[(size_t)(base + c) * 64 + qrow]);

    float L = 0.f;
    float o[8] = {0, 0, 0, 0, 0, 0, 0, 0};
    for (int c = 0; c < nchunk; c++) {
        const float mc = Ml[(size_t)(base + c) * 64 + qrow];
        const float lc = Ml[(size_t)(base + c) * 64 + 32 + qrow];
        const float w = (mc == -INFINITY) ? 0.f : expf(mc - M);
        L = fmaf(lc, w, L);
        const size_t ob = ((size_t)(base + c) * 32 + qrow) * 64 + d0;
        const float4 a0 = *(const float4*)(Opart + ob);
        const float4 a1 = *(const float4*)(Opart + ob + 4);
        o[0] = fmaf(a0.x, w, o[0]); o[1] = fmaf(a0.y, w, o[1]);
        o[2] = fmaf(a0.z, w, o[2]); o[3] = fmaf(a0.w, w, o[3]);
        o[4] = fmaf(a1.x, w, o[4]); o[5] = fmaf(a1.y, w, o[5]);
        o[6] = fmaf(a1.z, w, o[6]); o[7] = fmaf(a1.w, w, o[7]);
    }
    const float inv = 1.f / L;
    const int t = b * S_ + qt * 32 + qrow;
    float4 r0, r1;
    r0.x = o[0] * inv; r0.y = o[1] * inv; r0.z = o[2] * inv; r0.w = o[3] * inv;
    r1.x = o[4] * inv; r1.y = o[5] * inv; r1.z = o[6] * inv; r1.w = o[7] * inv;
    *(float4*)(out + (size_t)t * D_ + h * HD_ + d0) = r0;
    *(float4*)(out + (size_t)t * D_ + h * HD_ + d0 + 4) = r1;
}

// ---------------------------------------------------------------------------
// Gating + routing. bf16-rounded logits, top-2 lowest-index tie-break;
// scatters (token, weight) into per-expert lists; probs -> buffer.
// ---------------------------------------------------------------------------
__global__ __launch_bounds__(64) void gate_kernel(
    const ushort_t* __restrict__ xn2, const float* __restrict__ gate_w,
    int* __restrict__ cnt, int* __restrict__ tok, float* __restrict__ wt,
    float* __restrict__ probs)
{
    const int t = blockIdx.x;
    const int lane = threadIdx.x;
    float acc[8] = {0, 0, 0, 0, 0, 0, 0, 0};
    for (int d = lane; d < D_; d += 64) {
        const float xv = bf2f(xn2[(size_t)t * D_ + d]);
        const float4 g0 = ((const float4*)(gate_w + d * 8))[0];
        const float4 g1 = ((const float4*)(gate_w + d * 8))[1];
        acc[0] = fmaf(xv, bf2f(f2bf(g0.x)), acc[0]);
        acc[1] = fmaf(xv, bf2f(f2bf(g0.y)), acc[1]);
        acc[2] = fmaf(xv, bf2f(f2bf(g0.z)), acc[2]);
        acc[3] = fmaf(xv, bf2f(f2bf(g0.w)), acc[3]);
        acc[4] = fmaf(xv, bf2f(f2bf(g1.x)), acc[4]);
        acc[5] = fmaf(xv, bf2f(f2bf(g1.y)), acc[5]);
        acc[6] = fmaf(xv, bf2f(f2bf(g1.z)), acc[6]);
        acc[7] = fmaf(xv, bf2f(f2bf(g1.w)), acc[7]);
    }
#pragma unroll
    for (int e = 0; e < 8; e++) {
#pragma unroll
        for (int off = 32; off; off >>= 1) acc[e] += __shfl_xor(acc[e], off);
        acc[e] = bf2f(f2bf(acc[e]));   // bf16 result of the bf16 matmul
    }

    if (lane == 0) {
        int i1 = 0;
        for (int e = 1; e < 8; e++) if (acc[e] > acc[i1]) i1 = e;
        int i2 = (i1 == 0) ? 1 : 0;
        for (int e = 0; e < 8; e++) if (e != i1 && acc[e] > acc[i2]) i2 = e;
        const float e2 = expf(acc[i2] - acc[i1]);
        const float w1 = 1.f / (1.f + e2);
        const float w2 = e2 * w1;
        const int p1 = atomicAdd(&cnt[i1], 1);
        tok[i1 * T_ + p1] = t; wt[i1 * T_ + p1] = w1;
        const int p2 = atomicAdd(&cnt[i2], 1);
        tok[i2 * T_ + p2] = t; wt[i2 * T_ + p2] = w2;
        const float mx = acc[i1];
        float se = 0.f, pe[8];
        for (int e = 0; e < 8; e++) { pe[e] = expf(acc[e] - mx); se += pe[e]; }
        const float inv = 1.f / se;
        for (int e = 0; e < 8; e++) probs[t * 8 + e] = pe[e] * inv;
    }
}

__global__ void zero_route_kernel(int* __restrict__ cnt)
{
    if (threadIdx.x < 8) cnt[threadIdx.x] = 0;
}

// ---------------------------------------------------------------------------
// dist = probs.mean(0); lb = E * sum(dist^2); writes out tail.
// ---------------------------------------------------------------------------
__global__ __launch_bounds__(256) void reduce_dist_kernel(
    const float* __restrict__ probs, float* __restrict__ out)
{
    __shared__ float part[256];
    __shared__ float dist8[8];
    const int tid = threadIdx.x;
    const int e = tid & 7, chunk = tid >> 3;   // 32 chunks
    float s = 0.f;
    for (int t = chunk; t < T_; t += 32) s += probs[t * 8 + e];
    part[tid] = s;
    __syncthreads();
    if (tid < 8) {
        float tot = 0.f;
        for (int c = 0; c < 32; c++) tot += part[c * 8 + tid];
        const float dv = tot * (1.0f / T_);
        dist8[tid] = dv;
        out[(size_t)T_ * D_ + 1 + tid] = dv;
    }
    __syncthreads();
    if (tid == 0) {
        float s2 = 0.f;
        for (int k = 0; k < 8; k++) s2 += dist8[k] * dist8[k];
        out[(size_t)T_ * D_] = (float)E_ * s2;
    }
}

// ---------------------------------------------------------------------------
// Launch
// ---------------------------------------------------------------------------
extern "C" void kernel_launch(void* const* d_in, const int* in_sizes, int n_in,
                              void* d_out, int out_size, void* d_ws, size_t ws_size,
                              hipStream_t stream)
{
    const float* x      = (const float*)d_in[0];
    const float* ln1_g  = (const float*)d_in[1];
    const float* ln1_b  = (const float*)d_in[2];
    const float* ln2_g  = (const float*)d_in[3];
    const float* ln2_b  = (const float*)d_in[4];
    const float* w_qkv  = (const float*)d_in[5];
    const float* w_o    = (const float*)d_in[6];
    const float* gate_w = (const float*)d_in[7];
    const float* w_gate = (const float*)d_in[8];
    const float* w_up   = (const float*)d_in[9];
    const float* w_down = (const float*)d_in[10];
    float* out = (float*)d_out;

    char* ws = (char*)d_ws;
    size_t off = 0;
    auto alloc = [&](size_t bytes) { size_t o = off; off += (bytes + 255) & ~(size_t)255; return o; };
    // persistent-through-MoE region
    ushort_t* wguT  = (ushort_t*)(ws + alloc((size_t)E_ * GU_ * D_ * 2));   // 58.7 MB
    ushort_t* wdT   = (ushort_t*)(ws + alloc((size_t)E_ * D_ * HID_ * 2));  // 29.4 MB
    float*    xn    = (float*)   (ws + alloc((size_t)T_ * D_ * 4));
    ushort_t* xn2   = (ushort_t*)(ws + alloc((size_t)T_ * D_ * 2));
    int*      cnt   = (int*)     (ws + alloc(64));
    int*      tok   = (int*)     (ws + alloc((size_t)E_ * T_ * 4));
    float*    wt    = (float*)   (ws + alloc((size_t)E_ * T_ * 4));
    float*    probs = (float*)   (ws + alloc((size_t)T_ * E_ * 4));
    float*    ctab  = (float*)   (ws + alloc((size_t)S_ * 32 * 4));
    float*    stab  = (float*)   (ws + alloc((size_t)S_ * 32 * 4));
    // scratch union: [qkv 25.2MB | Opart 37.75MB | Ml 1.2MB] = 64.1MB
    // attnO/x1 alias into the (dead-after-pass1) qkv region; Hc aliases whole
    const size_t qkvBytes   = (size_t)T_ * D3_ * 4;
    const size_t opartBytes = (size_t)64 * NPART_ * 32 * 64 * 4;
    const size_t mlBytes    = (size_t)64 * NPART_ * 64 * 4;
    const size_t scratch0 = alloc(qkvBytes + opartBytes + mlBytes);
    float*    qkv   = (float*)   (ws + scratch0);
    float*    Opart = (float*)   (ws + scratch0 + qkvBytes);
    float*    Ml    = (float*)   (ws + scratch0 + qkvBytes + opartBytes);
    float*    attnO = (float*)   (ws + scratch0);                              // alias
    float*    x1    = (float*)   (ws + scratch0 + (size_t)T_ * D_ * 4);        // alias
    ushort_t* Hc    = (ushort_t*)(ws + scratch0);                              // alias
    (void)ws_size; (void)in_sizes; (void)n_in; (void)out_size;

    // weight transposes -> bf16 (N x K); gate/up interleaved into wguT
    hipLaunchKernelGGL(transpose_bf16_kernel, dim3(HID_ / 32, D_ / 32, E_), dim3(256), 0, stream,
                       w_gate, wguT, D_, HID_, 2, 0, (long)GU_ * D_);
    hipLaunchKernelGGL(transpose_bf16_kernel, dim3(HID_ / 32, D_ / 32, E_), dim3(256), 0, stream,
                       w_up, wguT, D_, HID_, 2, 1, (long)GU_ * D_);
    hipLaunchKernelGGL(transpose_bf16_kernel, dim3(D_ / 32, HID_ / 32, E_), dim3(256), 0, stream,
                       w_down, wdT, HID_, D_, 1, 0, (long)D_ * HID_);

    // RoPE tables
    hipLaunchKernelGGL(rope_table_kernel, dim3((S_ * 32 + 255) / 256), dim3(256), 0, stream,
                       ctab, stab);

    // LN1 (f32)
    hipLaunchKernelGGL(ln_kernel, dim3(T_), dim3(256), 0, stream,
                       x, ln1_g, ln1_b, xn, (ushort_t*)nullptr);

    // QKV f32 SGEMM: 128x64 tiles -> 48x16 = 768 blocks
    hipLaunchKernelGGL((sgemm_kernel<128>), dim3(D3_ / 64, T_ / 128), dim3(256), 0, stream,
                       xn, w_qkv, (const float*)nullptr, qkv, (float*)nullptr, T_, D3_, D_);

    // RoPE
    hipLaunchKernelGGL(rope_kernel, dim3(T_ * H_ * 32 / 256), dim3(256), 0, stream,
                       qkv, ctab, stab);

    // attention: split-K partials + combine
    hipLaunchKernelGGL(attn_part_kernel, dim3(8, 16, 64), dim3(256), 0, stream,
                       qkv, Opart, Ml);
    hipLaunchKernelGGL(attn_combine_kernel, dim3(16, 64), dim3(256), 0, stream,
                       Opart, Ml, attnO);

    // W_O SGEMM + residual -> x1 AND out (down_idx accumulates on out)
    hipLaunchKernelGGL((sgemm_kernel<64>), dim3(D_ / 64, T_ / 64), dim3(256), 0, stream,
                       attnO, w_o, x, x1, out, T_, D_, D_);

    // LN2 (bf16)
    hipLaunchKernelGGL(ln_kernel, dim3(T_), dim3(256), 0, stream,
                       x1, ln2_g, ln2_b, (float*)nullptr, xn2);

    // gating + routing + aux outputs
    hipLaunchKernelGGL(zero_route_kernel, dim3(1), dim3(64), 0, stream, cnt);
    hipLaunchKernelGGL(gate_kernel, dim3(T_), dim3(64), 0, stream,
                       xn2, gate_w, cnt, tok, wt, probs);
    hipLaunchKernelGGL(reduce_dist_kernel, dim3(1), dim3(256), 0, stream, probs, out);

    // MoE routed: fused gate+up (+silu), then weighted down accumulation
    hipLaunchKernelGGL(gateup_idx_kernel, dim3(GU_ / 128, T_ / 128, E_), dim3(256), 0, stream,
                       xn2, wguT, cnt, tok, Hc);
    hipLaunchKernelGGL(down_idx_kernel, dim3(D_ / 128, T_ / 128, E_), dim3(256), 0, stream,
                       Hc, wdT, cnt, tok, wt, out);
}

// Round 7
// 827.134 us; speedup vs baseline: 1.0365x; 1.0177x over previous
//
#include <hip/hip_runtime.h>
#include <hip/hip_bf16.h>
#include <math.h>

// ---------------------------------------------------------------------------
// Shapes (fixed by the problem)
// ---------------------------------------------------------------------------
#define B_    4
#define S_    512
#define D_    1024
#define T_    2048          // B*S tokens
#define H_    16
#define HD_   64
#define E_    8
#define HID_  1792
#define D3_   3072
#define GU_   (2 * HID_)    // 3584 interleaved gate/up columns
#define NPART_ 72           // partial chunks per (b,h): sum_{qt<16} (qt/2+1)

typedef unsigned short ushort_t;
typedef __bf16 bf16x8 __attribute__((ext_vector_type(8)));
typedef float  floatx4 __attribute__((ext_vector_type(4)));

__constant__ int kPrefix[16] = {0,1,2,4,6,9,12,16,20,25,30,36,42,49,56,64};

__device__ inline float bf2f(ushort_t u) {
    return __uint_as_float(((unsigned)u) << 16);
}
__device__ inline ushort_t f2bf(float f) {
    __hip_bfloat16 h = __float2bfloat16(f);
    return __builtin_bit_cast(ushort_t, h);
}

// async 16B/lane global->LDS; lds dest wave-uniform base (+lane*16 by HW)
__device__ __forceinline__ void gl2lds16(const ushort_t* g, ushort_t* l) {
    __builtin_amdgcn_global_load_lds(
        (const __attribute__((address_space(1))) void*)g,
        (__attribute__((address_space(3))) void*)l, 16, 0, 0);
}

// ---------------------------------------------------------------------------
// Transpose + fp32->bf16: in (z,R,C) f32 -> out[z*outEstride + (c*mul+add)*R + r]
// ---------------------------------------------------------------------------
__global__ __launch_bounds__(256) void transpose_bf16_kernel(
    const float* __restrict__ in, ushort_t* __restrict__ out,
    int R, int C, int mul, int add, long outEstride)
{
    __shared__ float tile[32][33];
    const int bx = blockIdx.x * 32;           // c
    const int by = blockIdx.y * 32;           // r
    const size_t iofs = (size_t)blockIdx.z * R * C;
    const size_t oofs = (size_t)blockIdx.z * outEstride;
    const int tx = threadIdx.x & 31;
    const int ty = threadIdx.x >> 5;          // 0..7
#pragma unroll
    for (int i = 0; i < 4; i++) {
        int r = by + ty + i * 8;
        tile[ty + i * 8][tx] = in[iofs + (size_t)r * C + bx + tx];
    }
    __syncthreads();
#pragma unroll
    for (int i = 0; i < 4; i++) {
        int c = bx + ty + i * 8;
        out[oofs + (size_t)(c * mul + add) * R + by + tx] = f2bf(tile[tx][ty + i * 8]);
    }
}

// ---------------------------------------------------------------------------
// LayerNorm: x (rows x 1024) f32 -> f32 out and/or bf16 out
// ---------------------------------------------------------------------------
__global__ __launch_bounds__(256) void ln_kernel(
    const float* __restrict__ x, const float* __restrict__ g,
    const float* __restrict__ b, float* __restrict__ outf,
    ushort_t* __restrict__ outb)
{
    const int t = blockIdx.x;
    const int tid = threadIdx.x;
    const int wave = tid >> 6, lane = tid & 63;
    const float4 v = ((const float4*)(x + (size_t)t * D_))[tid];

    float s = v.x + v.y + v.z + v.w;
#pragma unroll
    for (int off = 32; off; off >>= 1) s += __shfl_xor(s, off);
    __shared__ float red1[4];
    __shared__ float red2[4];
    if (lane == 0) red1[wave] = s;
    __syncthreads();
    const float mu = (red1[0] + red1[1] + red1[2] + red1[3]) * (1.0f / D_);

    const float dx = v.x - mu, dy = v.y - mu, dz = v.z - mu, dw = v.w - mu;
    float vs = dx * dx + dy * dy + dz * dz + dw * dw;
#pragma unroll
    for (int off = 32; off; off >>= 1) vs += __shfl_xor(vs, off);
    if (lane == 0) red2[wave] = vs;
    __syncthreads();
    const float var = (red2[0] + red2[1] + red2[2] + red2[3]) * (1.0f / D_);
    const float rs = 1.0f / sqrtf(var + 1e-5f);

    const float4 gg = ((const float4*)g)[tid];
    const float4 bb = ((const float4*)b)[tid];
    float4 o;
    o.x = dx * rs * gg.x + bb.x;
    o.y = dy * rs * gg.y + bb.y;
    o.z = dz * rs * gg.z + bb.z;
    o.w = dw * rs * gg.w + bb.w;
    if (outf) ((float4*)(outf + (size_t)t * D_))[tid] = o;
    if (outb) {
        ushort4 ob;
        ob.x = f2bf(o.x); ob.y = f2bf(o.y); ob.z = f2bf(o.z); ob.w = f2bf(o.w);
        ((ushort4*)(outb + (size_t)t * D_))[tid] = ob;
    }
}

// ---------------------------------------------------------------------------
// f32 SGEMM: tiles TM x 64, BK=16, 256 thr, (TM/16)x4 per thread.
// ---------------------------------------------------------------------------
template<int TM>
__global__ __launch_bounds__(256) void sgemm_kernel(
    const float* __restrict__ A, const float* __restrict__ B,
    const float* __restrict__ res, float* __restrict__ C,
    float* __restrict__ C2, int M, int N, int K)
{
    constexpr int RM  = TM / 16;
    constexpr int TPR = 256 / TM;
    constexpr int KF  = 16 / TPR;
    __shared__ float As[16][TM + 4];
    __shared__ float Bs[16][68];
    const int tid = threadIdx.x;
    const int m0 = blockIdx.y * TM, n0 = blockIdx.x * 64;
    const int tx = tid & 15, ty = tid >> 4;

    float acc[RM][4] = {};

    const int arow = tid / TPR;
    const int akk  = (tid % TPR) * KF;
    const int bk = tid >> 4;
    const int bc = (tid & 15) * 4;

    const float* Ap = A + (size_t)(m0 + arow) * K + akk;
    const float* Bp = B + (size_t)bk * N + n0 + bc;

    for (int k0 = 0; k0 < K; k0 += 16) {
        float av[KF];
#pragma unroll
        for (int f = 0; f < KF / 4; f++) {
            const float4 t = *(const float4*)(Ap + k0 + f * 4);
            av[f * 4 + 0] = t.x; av[f * 4 + 1] = t.y;
            av[f * 4 + 2] = t.z; av[f * 4 + 3] = t.w;
        }
        const float4 bv = *(const float4*)(Bp + (size_t)k0 * N);
        __syncthreads();
#pragma unroll
        for (int i = 0; i < KF; i++) As[akk + i][arow] = av[i];
        *(float4*)&Bs[bk][bc] = bv;
        __syncthreads();
#pragma unroll
        for (int k = 0; k < 16; k++) {
            float a[RM];
#pragma unroll
            for (int f = 0; f < RM / 4; f++) {
                const float4 t = *(const float4*)&As[k][ty * RM + f * 4];
                a[f * 4 + 0] = t.x; a[f * 4 + 1] = t.y;
                a[f * 4 + 2] = t.z; a[f * 4 + 3] = t.w;
            }
            const float4 bb = *(const float4*)&Bs[k][tx * 4];
            const float bj[4] = {bb.x, bb.y, bb.z, bb.w};
#pragma unroll
            for (int i = 0; i < RM; i++)
#pragma unroll
                for (int j = 0; j < 4; j++)
                    acc[i][j] = fmaf(a[i], bj[j], acc[i][j]);
        }
    }

#pragma unroll
    for (int i = 0; i < RM; i++) {
        const int row = m0 + ty * RM + i;
        const size_t base = (size_t)row * N + n0 + tx * 4;
        float4 o;
        o.x = acc[i][0]; o.y = acc[i][1]; o.z = acc[i][2]; o.w = acc[i][3];
        if (res) {
            const float4 r0 = *(const float4*)(res + base);
            o.x += r0.x; o.y += r0.y; o.z += r0.z; o.w += r0.w;
        }
        *(float4*)(C + base) = o;
        if (C2) *(float4*)(C2 + base) = o;
    }
}

// ---------------------------------------------------------------------------
// f32 SGEMM split-K: 128x64 tile, K-slice KS per z; writes Cpart[z].
// ---------------------------------------------------------------------------
__global__ __launch_bounds__(256) void sgemm_splitk_kernel(
    const float* __restrict__ A, const float* __restrict__ B,
    float* __restrict__ Cpart, int M, int N, int K, int KS)
{
    __shared__ float As[16][132];
    __shared__ float Bs[16][68];
    const int tid = threadIdx.x;
    const int m0 = blockIdx.y * 128, n0 = blockIdx.x * 64;
    const int z = blockIdx.z;
    const int kBegin = z * KS;
    const int tx = tid & 15, ty = tid >> 4;

    float acc[8][4] = {};

    const int arow = tid >> 1;           // 0..127
    const int akk  = (tid & 1) * 8;      // 0,8
    const int bk = tid >> 4;             // 0..15
    const int bc = (tid & 15) * 4;       // 0..60

    const float* Ap = A + (size_t)(m0 + arow) * K + kBegin + akk;
    const float* Bp = B + (size_t)(kBegin + bk) * N + n0 + bc;

    for (int k0 = 0; k0 < KS; k0 += 16) {
        float av[8];
#pragma unroll
        for (int f = 0; f < 2; f++) {
            const float4 t = *(const float4*)(Ap + k0 + f * 4);
            av[f * 4 + 0] = t.x; av[f * 4 + 1] = t.y;
            av[f * 4 + 2] = t.z; av[f * 4 + 3] = t.w;
        }
        const float4 bv = *(const float4*)(Bp + (size_t)k0 * N);
        __syncthreads();
#pragma unroll
        for (int i = 0; i < 8; i++) As[akk + i][arow] = av[i];
        *(float4*)&Bs[bk][bc] = bv;
        __syncthreads();
#pragma unroll
        for (int k = 0; k < 16; k++) {
            float a[8];
#pragma unroll
            for (int f = 0; f < 2; f++) {
                const float4 t = *(const float4*)&As[k][ty * 8 + f * 4];
                a[f * 4 + 0] = t.x; a[f * 4 + 1] = t.y;
                a[f * 4 + 2] = t.z; a[f * 4 + 3] = t.w;
            }
            const float4 bb = *(const float4*)&Bs[k][tx * 4];
            const float bj[4] = {bb.x, bb.y, bb.z, bb.w};
#pragma unroll
            for (int i = 0; i < 8; i++)
#pragma unroll
                for (int j = 0; j < 4; j++)
                    acc[i][j] = fmaf(a[i], bj[j], acc[i][j]);
        }
    }

    float* Cz = Cpart + (size_t)z * M * N;
#pragma unroll
    for (int i = 0; i < 8; i++) {
        const int row = m0 + ty * 8 + i;
        const size_t base = (size_t)row * N + n0 + tx * 4;
        float4 o;
        o.x = acc[i][0]; o.y = acc[i][1]; o.z = acc[i][2]; o.w = acc[i][3];
        *(float4*)(Cz + base) = o;
    }
}

// ---------------------------------------------------------------------------
// rope_add: qkv = P0 + P1 (split-K combine), rotate q/k cols, in-place to P0.
// grid (6, T): thread handles 2 consecutive elements.
// ---------------------------------------------------------------------------
__global__ __launch_bounds__(256) void rope_add_kernel(
    float* __restrict__ P0, const float* __restrict__ P1,
    const float* __restrict__ ctab, const float* __restrict__ stab)
{
    const int t = blockIdx.y;
    const int c2 = blockIdx.x * 256 + threadIdx.x;   // 0..1535
    const int col = c2 * 2;
    const size_t idx = (size_t)t * D3_ + col;
    const float2 a0 = *(const float2*)(P0 + idx);
    const float2 a1 = *(const float2*)(P1 + idx);
    float x0 = a0.x + a1.x;
    float x1 = a0.y + a1.y;
    if (col < 2 * D_) {
        const int pair = (col & 63) >> 1;
        const int s = t & (S_ - 1);
        const float c = ctab[s * 32 + pair];
        const float sn = stab[s * 32 + pair];
        const float y0 = x0 * c - x1 * sn;
        const float y1 = x0 * sn + x1 * c;
        x0 = y0; x1 = y1;
    }
    float2 o; o.x = x0; o.y = x1;
    *(float2*)(P0 + idx) = o;
}

// ---------------------------------------------------------------------------
// Routed fused gate+up MoE GEMM: rows gathered from per-expert token lists.
// ---------------------------------------------------------------------------
__global__ __launch_bounds__(256) void gateup_idx_kernel(
    const ushort_t* __restrict__ A, const ushort_t* __restrict__ Bgu,
    const int* __restrict__ cnt, const int* __restrict__ tok,
    ushort_t* __restrict__ Hc)
{
    const int e = blockIdx.z;
    const int cntE = cnt[e];
    const int row0 = blockIdx.y * 128;
    if (row0 >= cntE) return;
    const int col0 = blockIdx.x * 128;
    const ushort_t* Bt = Bgu + (size_t)e * GU_ * D_;
    ushort_t* Hp = Hc + (size_t)e * T_ * HID_;

    __shared__ __align__(16) ushort_t As[128 * 32];
    __shared__ __align__(16) ushort_t Bs[128 * 32];
    const int tid = threadIdx.x, w = tid >> 6, lane = tid & 63;
    const int lr = lane >> 2, lc = (lane & 3) * 8;
    const int wm = (w >> 1) * 64, wn = (w & 1) * 64;
    const int lm = lane & 15, lq = lane >> 4;

    floatx4 acc[4][4] = {};

    int r0c = row0 + w * 16 + lr;  if (r0c > cntE - 1) r0c = cntE - 1;
    int r1c = row0 + 64 + w * 16 + lr; if (r1c > cntE - 1) r1c = cntE - 1;
    const ushort_t* Ap0 = A + (size_t)tok[e * T_ + r0c] * D_ + lc;
    const ushort_t* Ap1 = A + (size_t)tok[e * T_ + r1c] * D_ + lc;
    const ushort_t* Bp = Bt + (size_t)(col0 + w * 16 + lr) * D_ + lc;
    ushort_t* lA = As + w * 512;
    ushort_t* lB = Bs + w * 512;

    for (int k0 = 0; k0 < D_; k0 += 32) {
        __syncthreads();
        gl2lds16(Ap0 + k0, lA);
        gl2lds16(Ap1 + k0, lA + 2048);
        gl2lds16(Bp + k0, lB);
        gl2lds16(Bp + k0 + (size_t)64 * D_, lB + 2048);
        __syncthreads();
        bf16x8 a[4], b[4];
#pragma unroll
        for (int i = 0; i < 4; i++)
            a[i] = *(const bf16x8*)(As + (wm + i * 16 + lm) * 32 + lq * 8);
#pragma unroll
        for (int j = 0; j < 4; j++)
            b[j] = *(const bf16x8*)(Bs + (wn + j * 16 + lm) * 32 + lq * 8);
#pragma unroll
        for (int i = 0; i < 4; i++)
#pragma unroll
            for (int j = 0; j < 4; j++)
                acc[i][j] = __builtin_amdgcn_mfma_f32_16x16x32_bf16(a[i], b[j], acc[i][j], 0, 0, 0);
    }

    // epilogue: adjacent lanes hold (gate, up) for the same hidden unit
#pragma unroll
    for (int i = 0; i < 4; i++)
#pragma unroll
        for (int j = 0; j < 4; j++)
#pragma unroll
            for (int r = 0; r < 4; r++) {
                const float v = acc[i][j][r];
                const float vp = __shfl_xor(v, 1);
                const float g = (lm & 1) ? vp : v;
                const float u = (lm & 1) ? v : vp;
                const float h = g / (1.f + __expf(-g)) * u;
                if (!(lm & 1)) {
                    const int row = row0 + wm + i * 16 + lq * 4 + r;
                    const int col = col0 + wn + j * 16 + lm;    // even
                    Hp[(size_t)row * HID_ + (col >> 1)] = f2bf(h);
                }
            }
}

// ---------------------------------------------------------------------------
// Routed MoE down GEMM, split-K: out[tok[r]] += wt[r] * (Hc[e] @ wd[e]^T).
// grid (8, 16, E*2): z -> (expert, k-slice of HID/2).
// ---------------------------------------------------------------------------
__global__ __launch_bounds__(256) void down_idx_kernel(
    const ushort_t* __restrict__ Hc, const ushort_t* __restrict__ Wd,
    const int* __restrict__ cnt, const int* __restrict__ tok,
    const float* __restrict__ wt, float* __restrict__ out)
{
    const int e = blockIdx.z >> 1;
    const int ks = blockIdx.z & 1;
    const int cntE = cnt[e];
    const int row0 = blockIdx.y * 128;
    if (row0 >= cntE) return;
    const int col0 = blockIdx.x * 128;
    const int kBegin = ks * (HID_ / 2);
    const ushort_t* A = Hc + (size_t)e * T_ * HID_;
    const ushort_t* Bt = Wd + (size_t)e * D_ * HID_;

    __shared__ __align__(16) ushort_t As[128 * 32];
    __shared__ __align__(16) ushort_t Bs[128 * 32];
    const int tid = threadIdx.x, w = tid >> 6, lane = tid & 63;
    const int lr = lane >> 2, lc = (lane & 3) * 8;
    const int wm = (w >> 1) * 64, wn = (w & 1) * 64;
    const int lm = lane & 15, lq = lane >> 4;

    floatx4 acc[4][4] = {};

    const ushort_t* Ap = A + (size_t)(row0 + w * 16 + lr) * HID_ + kBegin + lc;
    const ushort_t* Bp = Bt + (size_t)(col0 + w * 16 + lr) * HID_ + kBegin + lc;
    ushort_t* lA = As + w * 512;
    ushort_t* lB = Bs + w * 512;

    for (int k0 = 0; k0 < HID_ / 2; k0 += 32) {
        __syncthreads();
        gl2lds16(Ap + k0, lA);
        gl2lds16(Ap + k0 + (size_t)64 * HID_, lA + 2048);
        gl2lds16(Bp + k0, lB);
        gl2lds16(Bp + k0 + (size_t)64 * HID_, lB + 2048);
        __syncthreads();
        bf16x8 a[4], b[4];
#pragma unroll
        for (int i = 0; i < 4; i++)
            a[i] = *(const bf16x8*)(As + (wm + i * 16 + lm) * 32 + lq * 8);
#pragma unroll
        for (int j = 0; j < 4; j++)
            b[j] = *(const bf16x8*)(Bs + (wn + j * 16 + lm) * 32 + lq * 8);
#pragma unroll
        for (int i = 0; i < 4; i++)
#pragma unroll
            for (int j = 0; j < 4; j++)
                acc[i][j] = __builtin_amdgcn_mfma_f32_16x16x32_bf16(a[i], b[j], acc[i][j], 0, 0, 0);
    }

#pragma unroll
    for (int i = 0; i < 4; i++)
#pragma unroll
        for (int r = 0; r < 4; r++) {
            const int row = row0 + wm + i * 16 + lq * 4 + r;
            if (row < cntE) {
                const int t = tok[e * T_ + row];
                const float scale = wt[e * T_ + row];
#pragma unroll
                for (int j = 0; j < 4; j++) {
                    const int col = col0 + wn + j * 16 + lm;
                    atomicAdd(&out[(size_t)t * D_ + col], scale * acc[i][j][r]);
                }
            }
        }
}

// ---------------------------------------------------------------------------
// RoPE cos/sin tables (np f32 semantics via f64 pow/cos/sin)
// ---------------------------------------------------------------------------
__global__ __launch_bounds__(256) void rope_table_kernel(
    float* __restrict__ ctab, float* __restrict__ stab)
{
    const int i = blockIdx.x * 256 + threadIdx.x;   // S_*32
    if (i >= S_ * 32) return;
    const int s = i >> 5, p = i & 31;
    const double e = (double)(2 * p) / 64.0;
    const float pf = (float)pow(10000.0, e);
    const float invf = 1.0f / pf;
    const float fr = (float)s * invf;
    ctab[i] = (float)cos((double)fr);
    stab[i] = (float)sin((double)fr);
}

// ---------------------------------------------------------------------------
// Split-K flash attention, pass 1
// ---------------------------------------------------------------------------
__global__ __launch_bounds__(256) void attn_part_kernel(
    const float* __restrict__ qkv, float* __restrict__ Opart,
    float* __restrict__ Ml)
{
    const int qt = blockIdx.y;
    const int kc = blockIdx.x;
    if (kc > (qt >> 1)) return;
    const int bh = blockIdx.z;                 // b*16+h
    const int b = bh >> 4, h = bh & 15;
    const int q0 = qt * 32;
    const int c0 = kc * 64;
    const int pidx = bh * NPART_ + kPrefix[qt] + kc;

    __shared__ __align__(16) float kbuf[64][68];
    __shared__ __align__(16) float vbuf[64][68];
    __shared__ __align__(16) float qs[32][68];
    __shared__ __align__(16) float ps[4][8][68];

    const int tid = threadIdx.x, wave = tid >> 6, lane = tid & 63;

    for (int i = tid; i < 32 * 16; i += 256) {
        const int qi = i >> 4, g = i & 15;
        const int t = b * S_ + q0 + qi;
        *(float4*)&qs[qi][g * 4] =
            *(const float4*)(qkv + (size_t)t * D3_ + h * HD_ + g * 4);
    }
    for (int i = tid; i < 64 * 16; i += 256) {
        const int key = i >> 4, g = i & 15;
        const int t = b * S_ + c0 + key;
        *(float4*)&kbuf[key][g * 4] =
            *(const float4*)(qkv + (size_t)t * D3_ + D_ + h * HD_ + g * 4);
        *(float4*)&vbuf[key][g * 4] =
            *(const float4*)(qkv + (size_t)t * D3_ + 2 * D_ + h * HD_ + g * 4);
    }
    __syncthreads();

    const int kglob = c0 + lane;
    float sc[8];
#pragma unroll
    for (int qi = 0; qi < 8; qi++) sc[qi] = 0.f;
#pragma unroll 4
    for (int g = 0; g < 16; g++) {
        const float4 kv = *(const float4*)&kbuf[lane][g * 4];
#pragma unroll
        for (int qi = 0; qi < 8; qi++) {
            const float4 qv = *(const float4*)&qs[wave * 8 + qi][g * 4];
            float s = sc[qi];
            s = fmaf(qv.x, kv.x, s);
            s = fmaf(qv.y, kv.y, s);
            s = fmaf(qv.z, kv.z, s);
            s = fmaf(qv.w, kv.w, s);
            sc[qi] = s;
        }
    }
#pragma unroll
    for (int qi = 0; qi < 8; qi++) {
        const int s = q0 + wave * 8 + qi;
        float v = (kglob <= s) ? sc[qi] * 0.125f : -INFINITY;
        float cmax = v;
#pragma unroll
        for (int off = 32; off; off >>= 1) cmax = fmaxf(cmax, __shfl_xor(cmax, off));
        const float p = (v == -INFINITY) ? 0.f : expf(v - cmax);
        float psum = p;
#pragma unroll
        for (int off = 32; off; off >>= 1) psum += __shfl_xor(psum, off);
        ps[wave][qi][lane] = p;
        if (lane == 0) {
            Ml[(size_t)pidx * 64 + wave * 8 + qi] = cmax;
            Ml[(size_t)pidx * 64 + 32 + wave * 8 + qi] = psum;
        }
    }

    float O[8];
#pragma unroll
    for (int qi = 0; qi < 8; qi++) O[qi] = 0.f;
#pragma unroll 4
    for (int g = 0; g < 16; g++) {
        const float v0 = vbuf[g * 4 + 0][lane];
        const float v1 = vbuf[g * 4 + 1][lane];
        const float v2 = vbuf[g * 4 + 2][lane];
        const float v3 = vbuf[g * 4 + 3][lane];
#pragma unroll
        for (int qi = 0; qi < 8; qi++) {
            const float4 p4 = *(const float4*)&ps[wave][qi][g * 4];
            float o = O[qi];
            o = fmaf(p4.x, v0, o);
            o = fmaf(p4.y, v1, o);
            o = fmaf(p4.z, v2, o);
            o = fmaf(p4.w, v3, o);
            O[qi] = o;
        }
    }
#pragma unroll
    for (int qi = 0; qi < 8; qi++)
        Opart[((size_t)pidx * 32 + wave * 8 + qi) * 64 + lane] = O[qi];
}

// ---------------------------------------------------------------------------
// Split-K flash attention, pass 2: combine <=8 partials per (bh,qt).
// ---------------------------------------------------------------------------
__global__ __launch_bounds__(256) void attn_combine_kernel(
    const float* __restrict__ Opart, const float* __restrict__ Ml,
    float* __restrict__ out)
{
    const int qt = blockIdx.x, bh = blockIdx.y;
    const int b = bh >> 4, h = bh & 15;
    const int nchunk = (qt >> 1) + 1;
    const int base = bh * NPART_ + kPrefix[qt];
    const int tid = threadIdx.x;
    const int qrow = tid >> 3;            // 0..31
    const int d0 = (tid & 7) * 8;         // 0..56

    float M = -INFINITY;
    for (int c = 0; c < nchunk; c++)
        M = fmaxf(M, Ml[(size_t)(base + c) * 64 + qrow]);

    float L = 0.f;
    float o[8] = {0, 0, 0, 0, 0, 0, 0, 0};
    for (int c = 0; c < nchunk; c++) {
        const float mc = Ml[(size_t)(base + c) * 64 + qrow];
        const float lc = Ml[(size_t)(base + c) * 64 + 32 + qrow];
        const float w = (mc == -INFINITY) ? 0.f : expf(mc - M);
        L = fmaf(lc, w, L);
        const size_t ob = ((size_t)(base + c) * 32 + qrow) * 64 + d0;
        const float4 a0 = *(const float4*)(Opart + ob);
        const float4 a1 = *(const float4*)(Opart + ob + 4);
        o[0] = fmaf(a0.x, w, o[0]); o[1] = fmaf(a0.y, w, o[1]);
        o[2] = fmaf(a0.z, w, o[2]); o[3] = fmaf(a0.w, w, o[3]);
        o[4] = fmaf(a1.x, w, o[4]); o[5] = fmaf(a1.y, w, o[5]);
        o[6] = fmaf(a1.z, w, o[6]); o[7] = fmaf(a1.w, w, o[7]);
    }
    const float inv = 1.f / L;
    const int t = b * S_ + qt * 32 + qrow;
    float4 r0, r1;
    r0.x = o[0] * inv; r0.y = o[1] * inv; r0.z = o[2] * inv; r0.w = o[3] * inv;
    r1.x = o[4] * inv; r1.y = o[5] * inv; r1.z = o[6] * inv; r1.w = o[7] * inv;
    *(float4*)(out + (size_t)t * D_ + h * HD_ + d0) = r0;
    *(float4*)(out + (size_t)t * D_ + h * HD_ + d0 + 4) = r1;
}

// ---------------------------------------------------------------------------
// Gating + routing. bf16-rounded logits, top-2 lowest-index tie-break.
// ---------------------------------------------------------------------------
__global__ __launch_bounds__(64) void gate_kernel(
    const ushort_t* __restrict__ xn2, const float* __restrict__ gate_w,
    int* __restrict__ cnt, int* __restrict__ tok, float* __restrict__ wt,
    float* __restrict__ probs)
{
    const int t = blockIdx.x;
    const int lane = threadIdx.x;
    float acc[8] = {0, 0, 0, 0, 0, 0, 0, 0};
    for (int d = lane; d < D_; d += 64) {
        const float xv = bf2f(xn2[(size_t)t * D_ + d]);
        const float4 g0 = ((const float4*)(gate_w + d * 8))[0];
        const float4 g1 = ((const float4*)(gate_w + d * 8))[1];
        acc[0] = fmaf(xv, bf2f(f2bf(g0.x)), acc[0]);
        acc[1] = fmaf(xv, bf2f(f2bf(g0.y)), acc[1]);
        acc[2] = fmaf(xv, bf2f(f2bf(g0.z)), acc[2]);
        acc[3] = fmaf(xv, bf2f(f2bf(g0.w)), acc[3]);
        acc[4] = fmaf(xv, bf2f(f2bf(g1.x)), acc[4]);
        acc[5] = fmaf(xv, bf2f(f2bf(g1.y)), acc[5]);
        acc[6] = fmaf(xv, bf2f(f2bf(g1.z)), acc[6]);
        acc[7] = fmaf(xv, bf2f(f2bf(g1.w)), acc[7]);
    }
#pragma unroll
    for (int e = 0; e < 8; e++) {
#pragma unroll
        for (int off = 32; off; off >>= 1) acc[e] += __shfl_xor(acc[e], off);
        acc[e] = bf2f(f2bf(acc[e]));   // bf16 result of the bf16 matmul
    }

    if (lane == 0) {
        int i1 = 0;
        for (int e = 1; e < 8; e++) if (acc[e] > acc[i1]) i1 = e;
        int i2 = (i1 == 0) ? 1 : 0;
        for (int e = 0; e < 8; e++) if (e != i1 && acc[e] > acc[i2]) i2 = e;
        const float e2 = expf(acc[i2] - acc[i1]);
        const float w1 = 1.f / (1.f + e2);
        const float w2 = e2 * w1;
        const int p1 = atomicAdd(&cnt[i1], 1);
        tok[i1 * T_ + p1] = t; wt[i1 * T_ + p1] = w1;
        const int p2 = atomicAdd(&cnt[i2], 1);
        tok[i2 * T_ + p2] = t; wt[i2 * T_ + p2] = w2;
        const float mx = acc[i1];
        float se = 0.f, pe[8];
        for (int e = 0; e < 8; e++) { pe[e] = expf(acc[e] - mx); se += pe[e]; }
        const float inv = 1.f / se;
        for (int e = 0; e < 8; e++) probs[t * 8 + e] = pe[e] * inv;
    }
}

__global__ void zero_route_kernel(int* __restrict__ cnt)
{
    if (threadIdx.x < 8) cnt[threadIdx.x] = 0;
}

// ---------------------------------------------------------------------------
// dist = probs.mean(0); lb = E * sum(dist^2); writes out tail.
// ---------------------------------------------------------------------------
__global__ __launch_bounds__(256) void reduce_dist_kernel(
    const float* __restrict__ probs, float* __restrict__ out)
{
    __shared__ float part[256];
    __shared__ float dist8[8];
    const int tid = threadIdx.x;
    const int e = tid & 7, chunk = tid >> 3;   // 32 chunks
    float s = 0.f;
    for (int t = chunk; t < T_; t += 32) s += probs[t * 8 + e];
    part[tid] = s;
    __syncthreads();
    if (tid < 8) {
        float tot = 0.f;
        for (int c = 0; c < 32; c++) tot += part[c * 8 + tid];
        const float dv = tot * (1.0f / T_);
        dist8[tid] = dv;
        out[(size_t)T_ * D_ + 1 + tid] = dv;
    }
    __syncthreads();
    if (tid == 0) {
        float s2 = 0.f;
        for (int k = 0; k < 8; k++) s2 += dist8[k] * dist8[k];
        out[(size_t)T_ * D_] = (float)E_ * s2;
    }
}

// ---------------------------------------------------------------------------
// Launch
// ---------------------------------------------------------------------------
extern "C" void kernel_launch(void* const* d_in, const int* in_sizes, int n_in,
                              void* d_out, int out_size, void* d_ws, size_t ws_size,
                              hipStream_t stream)
{
    const float* x      = (const float*)d_in[0];
    const float* ln1_g  = (const float*)d_in[1];
    const float* ln1_b  = (const float*)d_in[2];
    const float* ln2_g  = (const float*)d_in[3];
    const float* ln2_b  = (const float*)d_in[4];
    const float* w_qkv  = (const float*)d_in[5];
    const float* w_o    = (const float*)d_in[6];
    const float* gate_w = (const float*)d_in[7];
    const float* w_gate = (const float*)d_in[8];
    const float* w_up   = (const float*)d_in[9];
    const float* w_down = (const float*)d_in[10];
    float* out = (float*)d_out;

    char* ws = (char*)d_ws;
    size_t off = 0;
    auto alloc = [&](size_t bytes) { size_t o = off; off += (bytes + 255) & ~(size_t)255; return o; };
    // persistent-through-MoE region
    ushort_t* wguT  = (ushort_t*)(ws + alloc((size_t)E_ * GU_ * D_ * 2));   // 58.7 MB
    ushort_t* wdT   = (ushort_t*)(ws + alloc((size_t)E_ * D_ * HID_ * 2));  // 29.4 MB
    float*    xn    = (float*)   (ws + alloc((size_t)T_ * D_ * 4));
    ushort_t* xn2   = (ushort_t*)(ws + alloc((size_t)T_ * D_ * 2));
    int*      cnt   = (int*)     (ws + alloc(64));
    int*      tok   = (int*)     (ws + alloc((size_t)E_ * T_ * 4));
    float*    wt    = (float*)   (ws + alloc((size_t)E_ * T_ * 4));
    float*    probs = (float*)   (ws + alloc((size_t)T_ * E_ * 4));
    float*    ctab  = (float*)   (ws + alloc((size_t)S_ * 32 * 4));
    float*    stab  = (float*)   (ws + alloc((size_t)S_ * 32 * 4));
    // scratch union (64.1 MB peak, aliased by lifetime):
    //   phase A: qkvP0 [0,25.2) + qkvP1 [25.2,50.4)      (QKV split-K)
    //   phase B: qkv=P0 [0,25.2) + Opart [25.2,63) + Ml [63,64.1)
    //   phase C: attnO [0,8) + x1 [8,16) + Opart/Ml live
    //   phase D: Hc [0,58.7)
    const size_t qkvBytes   = (size_t)T_ * D3_ * 4;
    const size_t opartBytes = (size_t)64 * NPART_ * 32 * 64 * 4;
    const size_t mlBytes    = (size_t)64 * NPART_ * 64 * 4;
    const size_t scratch0 = alloc(qkvBytes + opartBytes + mlBytes);
    float*    qkvP0 = (float*)   (ws + scratch0);
    float*    qkvP1 = (float*)   (ws + scratch0 + qkvBytes);          // also Opart
    float*    Opart = (float*)   (ws + scratch0 + qkvBytes);
    float*    Ml    = (float*)   (ws + scratch0 + qkvBytes + opartBytes);
    float*    attnO = (float*)   (ws + scratch0);                     // alias P0
    float*    x1    = (float*)   (ws + scratch0 + (size_t)T_ * D_ * 4);
    ushort_t* Hc    = (ushort_t*)(ws + scratch0);                     // alias all
    (void)ws_size; (void)in_sizes; (void)n_in; (void)out_size;

    // weight transposes -> bf16 (N x K); gate/up interleaved into wguT
    hipLaunchKernelGGL(transpose_bf16_kernel, dim3(HID_ / 32, D_ / 32, E_), dim3(256), 0, stream,
                       w_gate, wguT, D_, HID_, 2, 0, (long)GU_ * D_);
    hipLaunchKernelGGL(transpose_bf16_kernel, dim3(HID_ / 32, D_ / 32, E_), dim3(256), 0, stream,
                       w_up, wguT, D_, HID_, 2, 1, (long)GU_ * D_);
    hipLaunchKernelGGL(transpose_bf16_kernel, dim3(D_ / 32, HID_ / 32, E_), dim3(256), 0, stream,
                       w_down, wdT, HID_, D_, 1, 0, (long)D_ * HID_);

    // RoPE tables
    hipLaunchKernelGGL(rope_table_kernel, dim3((S_ * 32 + 255) / 256), dim3(256), 0, stream,
                       ctab, stab);

    // LN1 (f32)
    hipLaunchKernelGGL(ln_kernel, dim3(T_), dim3(256), 0, stream,
                       x, ln1_g, ln1_b, xn, (ushort_t*)nullptr);

    // QKV f32 SGEMM, split-K=2: grid (48,16,2) = 1536 blocks
    hipLaunchKernelGGL(sgemm_splitk_kernel, dim3(D3_ / 64, T_ / 128, 2), dim3(256), 0, stream,
                       xn, w_qkv, qkvP0, T_, D3_, D_, D_ / 2);

    // combine K-slices + RoPE (in-place into qkvP0)
    hipLaunchKernelGGL(rope_add_kernel, dim3(6, T_), dim3(256), 0, stream,
                       qkvP0, qkvP1, ctab, stab);

    // attention: split-K partials + combine
    hipLaunchKernelGGL(attn_part_kernel, dim3(8, 16, 64), dim3(256), 0, stream,
                       qkvP0, Opart, Ml);
    hipLaunchKernelGGL(attn_combine_kernel, dim3(16, 64), dim3(256), 0, stream,
                       Opart, Ml, attnO);

    // W_O SGEMM + residual -> x1 AND out (down_idx accumulates on out)
    hipLaunchKernelGGL((sgemm_kernel<64>), dim3(D_ / 64, T_ / 64), dim3(256), 0, stream,
                       attnO, w_o, x, x1, out, T_, D_, D_);

    // LN2 (bf16)
    hipLaunchKernelGGL(ln_kernel, dim3(T_), dim3(256), 0, stream,
                       x1, ln2_g, ln2_b, (float*)nullptr, xn2);

    // gating + routing + aux outputs
    hipLaunchKernelGGL(zero_route_kernel, dim3(1), dim3(64), 0, stream, cnt);
    hipLaunchKernelGGL(gate_kernel, dim3(T_), dim3(64), 0, stream,
                       xn2, gate_w, cnt, tok, wt, probs);
    hipLaunchKernelGGL(reduce_dist_kernel, dim3(1), dim3(256), 0, stream, probs, out);

    // MoE routed: fused gate+up (+silu), then weighted down (split-K=2)
    hipLaunchKernelGGL(gateup_idx_kernel, dim3(GU_ / 128, T_ / 128, E_), dim3(256), 0, stream,
                       xn2, wguT, cnt, tok, Hc);
    hipLaunchKernelGGL(down_idx_kernel, dim3(D_ / 128, T_ / 128, E_ * 2), dim3(256), 0, stream,
                       Hc, wdT, cnt, tok, wt, out);
}